// Round 1
// baseline (2126.741 us; speedup 1.0000x reference)
//
#include <hip/hip_runtime.h>
#include <cstdint>
#include <cstddef>

// Problem constants (from reference)
#define D_MODEL 1024
#define D_INNER 2048
#define NSTATE  16
#define DTRANK  64
#define BATCH   2
#define SEQLEN  2048
#define BL      (BATCH*SEQLEN)   // 4096 tokens

__device__ __forceinline__ float softplusf(float x) {
    // jax.nn.softplus = logaddexp(x, 0) = max(x,0) + log1p(exp(-|x|))
    return fmaxf(x, 0.f) + log1pf(expf(-fabsf(x)));
}
__device__ __forceinline__ float siluf(float x) {
    return x / (1.f + expf(-x));
}

// ---- lbp[n,r] = lora_B[n,r] * mask[n] * 2.0 ----
__global__ __launch_bounds__(256) void premul_kernel(
        const float* __restrict__ lb, const float* __restrict__ mask,
        float* __restrict__ out, int total) {
    int i = blockIdx.x * 256 + threadIdx.x;
    if (i < total) out[i] = lb[i] * mask[i >> 4] * 2.0f;
}

// ---- T[m,r] = sum_k X[m,k] * LA[r,k]   (r < 16) ----
// 16 lanes per r; block handles one row m. float4 coalesced loads.
__global__ __launch_bounds__(256) void lora_t_kernel(
        const float* __restrict__ X, int ldx,
        const float* __restrict__ LA, int K,
        float* __restrict__ T) {
    int m = blockIdx.x;
    int r = threadIdx.x >> 4;   // 0..15
    int l = threadIdx.x & 15;   // 0..15
    const float* xrow = X + (size_t)m * ldx;
    const float* arow = LA + (size_t)r * K;
    float s = 0.f;
    for (int k = 4 * l; k < K; k += 64) {
        float4 xv = *(const float4*)(xrow + k);
        float4 av = *(const float4*)(arow + k);
        s += xv.x * av.x + xv.y * av.y + xv.z * av.z + xv.w * av.w;
    }
    #pragma unroll
    for (int o = 8; o; o >>= 1) s += __shfl_xor(s, o, 16);
    if (l == 0) T[(size_t)m * 16 + r] = s;
}

// ---- fp32 tiled GEMM:  C[m,n] = sum_k A[m,k] * W[n,k]  (+ epilogue) ----
// BM=BN=128, BK=8, 256 threads, 8x8 micro-tile (strided by 16 -> conflict-free
// LDS reads, coalesced C stores).
// EPI==0: plain store. EPI==1: LoRA fused as 2 extra K-tiles sourced from
//         Xt[M,16] and Wt[N,16] (Wt premultiplied by mask*2).
// EPI==2: softplus(v + bias[n]).
template<int EPI>
__global__ __launch_bounds__(256) void gemm_kernel(
        const float* __restrict__ A, int lda,
        const float* __restrict__ W,
        float* __restrict__ C, int ldc,
        int M, int N, int K,
        const float* __restrict__ Xt,
        const float* __restrict__ Wt,
        const float* __restrict__ bias) {
    __shared__ float As[8][128];
    __shared__ float Bs[8][128];
    const int tid = threadIdx.x;
    const int tx = tid & 15, ty = tid >> 4;
    const int bn0 = blockIdx.x * 128, bm0 = blockIdx.y * 128;
    const int lrow = tid >> 1;        // 0..127
    const int lk   = (tid & 1) * 4;   // 0 or 4
    const int nk_main = K >> 3;
    const int nk = nk_main + (EPI == 1 ? 2 : 0);

    float acc[8][8];
    #pragma unroll
    for (int i = 0; i < 8; ++i)
        #pragma unroll
        for (int j = 0; j < 8; ++j) acc[i][j] = 0.f;

    float4 av, wv;
    {   // kt = 0 prologue load
        av = *(const float4*)(A + (size_t)(bm0 + lrow) * lda + lk);
        int n = bn0 + lrow;
        wv = (n < N) ? *(const float4*)(W + (size_t)n * K + lk)
                     : make_float4(0.f, 0.f, 0.f, 0.f);
    }
    for (int kt = 0; kt < nk; ++kt) {
        __syncthreads();
        As[lk + 0][lrow] = av.x; As[lk + 1][lrow] = av.y;
        As[lk + 2][lrow] = av.z; As[lk + 3][lrow] = av.w;
        Bs[lk + 0][lrow] = wv.x; Bs[lk + 1][lrow] = wv.y;
        Bs[lk + 2][lrow] = wv.z; Bs[lk + 3][lrow] = wv.w;
        __syncthreads();
        int kt1 = kt + 1;
        if (kt1 < nk) {
            int n = bn0 + lrow;
            if (EPI == 1 && kt1 >= nk_main) {
                int r = kt1 * 8 - K + lk;   // 0..15 within the 16-wide LoRA rank
                av = *(const float4*)(Xt + (size_t)(bm0 + lrow) * 16 + r);
                wv = (n < N) ? *(const float4*)(Wt + (size_t)n * 16 + r)
                             : make_float4(0.f, 0.f, 0.f, 0.f);
            } else {
                av = *(const float4*)(A + (size_t)(bm0 + lrow) * lda + (size_t)kt1 * 8 + lk);
                wv = (n < N) ? *(const float4*)(W + (size_t)n * K + (size_t)kt1 * 8 + lk)
                             : make_float4(0.f, 0.f, 0.f, 0.f);
            }
        }
        #pragma unroll
        for (int k = 0; k < 8; ++k) {
            float a[8], b[8];
            #pragma unroll
            for (int i = 0; i < 8; ++i) a[i] = As[k][ty + 16 * i];
            #pragma unroll
            for (int j = 0; j < 8; ++j) b[j] = Bs[k][tx + 16 * j];
            #pragma unroll
            for (int i = 0; i < 8; ++i)
                #pragma unroll
                for (int j = 0; j < 8; ++j)
                    acc[i][j] = fmaf(a[i], b[j], acc[i][j]);
        }
    }
    #pragma unroll
    for (int i = 0; i < 8; ++i) {
        int m = bm0 + ty + 16 * i;
        #pragma unroll
        for (int j = 0; j < 8; ++j) {
            int n = bn0 + tx + 16 * j;
            if (n < N) {
                float v = acc[i][j];
                if (EPI == 2) v = softplusf(v + bias[n]);
                C[(size_t)m * ldc + n] = v;
            }
        }
    }
}

// ---- depthwise causal conv(d_conv=4) + bias + SiLU over xs = xz[:, :, :2048] ----
__global__ __launch_bounds__(256) void conv_silu_kernel(
        const float* __restrict__ xz, const float* __restrict__ cw,
        const float* __restrict__ cb, float* __restrict__ u) {
    int idx = blockIdx.x * 256 + threadIdx.x;   // over BL*D_INNER
    int d  = idx & (D_INNER - 1);
    int bl = idx >> 11;
    int l  = bl & (SEQLEN - 1);
    const float* base = xz + (size_t)bl * 4096 + d;
    float4 w = *(const float4*)(cw + d * 4);
    float s = cb[d];
    if (l >= 3) s = fmaf(base[-3 * 4096], w.x, s);
    if (l >= 2) s = fmaf(base[-2 * 4096], w.y, s);
    if (l >= 1) s = fmaf(base[-1 * 4096], w.z, s);
    s = fmaf(base[0], w.w, s);
    u[idx] = s * (1.f / (1.f + expf(-s)));      // SiLU
}

// ---- selective scan + Dp skip + SiLU(z) gating ----
// 16 lanes per (b,d) row, one lane per state n. Sequential over t with
// explicit next-step prefetch. Output yg may alias delta (read-before-write
// per t in wave program order).
__global__ __launch_bounds__(256) void scan_kernel(
        const float* __restrict__ delta, const float* __restrict__ u,
        const float* __restrict__ xdbl, const float* __restrict__ xz,
        const float* __restrict__ A_log, const float* __restrict__ Dp,
        float* __restrict__ yg) {
    const int tid = threadIdx.x;
    const int n = tid & 15;
    const int row = blockIdx.x * 16 + (tid >> 4);   // 0..B*D-1
    const int b = row >> 11;
    const int d = row & (D_INNER - 1);
    const float An = -expf(A_log[d * 16 + n]);
    const float Dd = Dp[d];
    const float* dl = delta + (size_t)b * SEQLEN * D_INNER + d;
    const float* uu = u     + (size_t)b * SEQLEN * D_INNER + d;
    const float* bc = xdbl  + (size_t)b * SEQLEN * 96;
    const float* zz = xz    + (size_t)b * SEQLEN * 4096 + D_INNER + d;
    float* yo = yg + (size_t)b * SEQLEN * D_INNER + d;
    float h = 0.f;
    float dv = dl[0], uv = uu[0], Bn = bc[64 + n], Cn = bc[80 + n], zv = zz[0];
    for (int t = 0; t < SEQLEN; ++t) {
        float dv2 = 0.f, uv2 = 0.f, Bn2 = 0.f, Cn2 = 0.f, zv2 = 0.f;
        if (t + 1 < SEQLEN) {
            size_t o = (size_t)(t + 1);
            dv2 = dl[o * D_INNER];
            uv2 = uu[o * D_INNER];
            Bn2 = bc[o * 96 + 64 + n];
            Cn2 = bc[o * 96 + 80 + n];
            zv2 = zz[o * 4096];
        }
        float dA = expf(dv * An);
        h = fmaf(dA, h, dv * uv * Bn);
        float p = h * Cn;
        #pragma unroll
        for (int o2 = 8; o2; o2 >>= 1) p += __shfl_xor(p, o2, 16);
        if (n == 0) {
            float yv = fmaf(uv, Dd, p);
            yo[(size_t)t * D_INNER] = yv * (zv / (1.f + expf(-zv)));
        }
        dv = dv2; uv = uv2; Bn = Bn2; Cn = Cn2; zv = zv2;
    }
}

extern "C" void kernel_launch(void* const* d_in, const int* in_sizes, int n_in,
                              void* d_out, int out_size, void* d_ws, size_t ws_size,
                              hipStream_t stream) {
    const float* x        = (const float*)d_in[0];
    const float* w_in     = (const float*)d_in[1];
    const float* lA_in    = (const float*)d_in[2];
    const float* lB_in    = (const float*)d_in[3];
    const float* mask_in  = (const float*)d_in[4];
    const float* conv_w   = (const float*)d_in[5];
    const float* conv_b   = (const float*)d_in[6];
    const float* w_xp     = (const float*)d_in[7];
    const float* w_dt     = (const float*)d_in[8];
    const float* b_dt     = (const float*)d_in[9];
    const float* A_log    = (const float*)d_in[10];
    const float* Dp       = (const float*)d_in[11];
    const float* w_out    = (const float*)d_in[12];
    const float* lA_out   = (const float*)d_in[13];
    const float* lB_out   = (const float*)d_in[14];
    const float* mask_out = (const float*)d_in[15];

    // Workspace layout (floats). Total = 34,095,104 f32 = 130.05 MB.
    float* ws    = (float*)d_ws;
    float* xz    = ws;                              // [BL,4096]  16,777,216
    float* u     = xz    + (size_t)BL * 4096;       // [BL,2048]   8,388,608
    float* delta = u     + (size_t)BL * D_INNER;    // [BL,2048]   8,388,608 (also yg)
    float* xdbl  = delta + (size_t)BL * D_INNER;    // [BL,96]       393,216
    float* t16   = xdbl  + (size_t)BL * 96;         // [BL,16]        65,536
    float* lbin  = t16   + (size_t)BL * 16;         // [4096,16]      65,536
    float* lbout = lbin  + (size_t)4096 * 16;       // [1024,16]      16,384

    // 1) premultiply LoRA B by mask*2
    premul_kernel<<<(4096 * 16 + 255) / 256, 256, 0, stream>>>(lB_in, mask_in, lbin, 4096 * 16);
    premul_kernel<<<(1024 * 16 + 255) / 256, 256, 0, stream>>>(lB_out, mask_out, lbout, 1024 * 16);
    // 2) t16 = x @ lora_A_in^T
    lora_t_kernel<<<BL, 256, 0, stream>>>(x, D_MODEL, lA_in, D_MODEL, t16);
    // 3) xz = x @ w_in^T + t16 @ lbin^T   (LoRA as K-extension)
    gemm_kernel<1><<<dim3(4096 / 128, BL / 128), 256, 0, stream>>>(
        x, D_MODEL, w_in, xz, 4096, BL, 4096, D_MODEL, t16, lbin, nullptr);
    // 4) u = silu(causal_dwconv(xz[:, :, :2048]) + conv_b)
    conv_silu_kernel<<<(BL * D_INNER) / 256, 256, 0, stream>>>(xz, conv_w, conv_b, u);
    // 5) xdbl = u @ w_xproj^T   [BL, 96]
    gemm_kernel<0><<<dim3(1, BL / 128), 256, 0, stream>>>(
        u, D_INNER, w_xp, xdbl, 96, BL, 96, D_INNER, nullptr, nullptr, nullptr);
    // 6) delta = softplus(xdbl[:, :64] @ w_dt^T + b_dt)   [BL, 2048]
    gemm_kernel<2><<<dim3(D_INNER / 128, BL / 128), 256, 0, stream>>>(
        xdbl, 96, w_dt, delta, D_INNER, BL, D_INNER, DTRANK, nullptr, nullptr, b_dt);
    // 7) selective scan + gating; yg aliases delta
    scan_kernel<<<(BATCH * D_INNER) / 16, 256, 0, stream>>>(
        delta, u, xdbl, xz, A_log, Dp, delta);
    // 8) t16 = yg @ lora_A_out^T
    lora_t_kernel<<<BL, 256, 0, stream>>>(delta, D_INNER, lA_out, D_INNER, t16);
    // 9) out = yg @ w_out^T + t16 @ lbout^T
    gemm_kernel<1><<<dim3(D_MODEL / 128, BL / 128), 256, 0, stream>>>(
        delta, D_INNER, w_out, (float*)d_out, D_MODEL, BL, D_MODEL, D_INNER, t16, lbout, nullptr);
}

// Round 2
// 1269.382 us; speedup vs baseline: 1.6754x; 1.6754x over previous
//
#include <hip/hip_runtime.h>
#include <cstdint>
#include <cstddef>

// Problem constants (from reference)
#define D_MODEL 1024
#define D_INNER 2048
#define NSTATE  16
#define DTRANK  64
#define BATCH   2
#define SEQLEN  2048
#define BL      (BATCH*SEQLEN)   // 4096 tokens
#define NSEG    8
#define TSEG    (SEQLEN/NSEG)    // 256
#define SKX     8                // split-K factor for x_proj
#define KCH     (D_INNER/SKX)    // 256

__device__ __forceinline__ float softplusf(float x) {
    return fmaxf(x, 0.f) + log1pf(expf(-fabsf(x)));
}

// ---- lbp[n,r] = lora_B[n,r] * mask[n] * 2.0 ----
__global__ __launch_bounds__(256) void premul_kernel(
        const float* __restrict__ lb, const float* __restrict__ mask,
        float* __restrict__ out, int total) {
    int i = blockIdx.x * 256 + threadIdx.x;
    if (i < total) out[i] = lb[i] * mask[i >> 4] * 2.0f;
}

// ---- T[m,r] = sum_k X[m,k] * LA[r,k]   (r < 16) ----
__global__ __launch_bounds__(256) void lora_t_kernel(
        const float* __restrict__ X, int ldx,
        const float* __restrict__ LA, int K,
        float* __restrict__ T) {
    int m = blockIdx.x;
    int r = threadIdx.x >> 4;
    int l = threadIdx.x & 15;
    const float* xrow = X + (size_t)m * ldx;
    const float* arow = LA + (size_t)r * K;
    float s = 0.f;
    for (int k = 4 * l; k < K; k += 64) {
        float4 xv = *(const float4*)(xrow + k);
        float4 av = *(const float4*)(arow + k);
        s += xv.x * av.x + xv.y * av.y + xv.z * av.z + xv.w * av.w;
    }
    #pragma unroll
    for (int o = 8; o; o >>= 1) s += __shfl_xor(s, o, 16);
    if (l == 0) T[(size_t)m * 16 + r] = s;
}

// ---- fp32 tiled GEMM:  C[m,n] = sum_k A[m,k] * W[n,k]  (+ epilogue) ----
// EPI==0: plain. EPI==1: +LoRA as 2 extra K-tiles. EPI==2: softplus(v+bias).
// kchunk != 0: split-K over blockIdx.z (A,W advance by z*kchunk; C by z*M*ldc).
template<int EPI>
__global__ __launch_bounds__(256) void gemm_kernel(
        const float* __restrict__ A, int lda,
        const float* __restrict__ W, int ldw,
        float* __restrict__ C, int ldc,
        int M, int N, int K, int kchunk,
        const float* __restrict__ Xt,
        const float* __restrict__ Wt,
        const float* __restrict__ bias) {
    __shared__ float As[8][128];
    __shared__ float Bs[8][128];
    if (kchunk) {
        A += (size_t)blockIdx.z * kchunk;
        W += (size_t)blockIdx.z * kchunk;
        C += (size_t)blockIdx.z * M * ldc;
    }
    const int tid = threadIdx.x;
    const int tx = tid & 15, ty = tid >> 4;
    const int bn0 = blockIdx.x * 128, bm0 = blockIdx.y * 128;
    const int lrow = tid >> 1;
    const int lk   = (tid & 1) * 4;
    const int nk_main = K >> 3;
    const int nk = nk_main + (EPI == 1 ? 2 : 0);

    float acc[8][8];
    #pragma unroll
    for (int i = 0; i < 8; ++i)
        #pragma unroll
        for (int j = 0; j < 8; ++j) acc[i][j] = 0.f;

    float4 av, wv;
    {
        av = *(const float4*)(A + (size_t)(bm0 + lrow) * lda + lk);
        int n = bn0 + lrow;
        wv = (n < N) ? *(const float4*)(W + (size_t)n * ldw + lk)
                     : make_float4(0.f, 0.f, 0.f, 0.f);
    }
    for (int kt = 0; kt < nk; ++kt) {
        __syncthreads();
        As[lk + 0][lrow] = av.x; As[lk + 1][lrow] = av.y;
        As[lk + 2][lrow] = av.z; As[lk + 3][lrow] = av.w;
        Bs[lk + 0][lrow] = wv.x; Bs[lk + 1][lrow] = wv.y;
        Bs[lk + 2][lrow] = wv.z; Bs[lk + 3][lrow] = wv.w;
        __syncthreads();
        int kt1 = kt + 1;
        if (kt1 < nk) {
            int n = bn0 + lrow;
            if (EPI == 1 && kt1 >= nk_main) {
                int r = kt1 * 8 - K + lk;
                av = *(const float4*)(Xt + (size_t)(bm0 + lrow) * 16 + r);
                wv = (n < N) ? *(const float4*)(Wt + (size_t)n * 16 + r)
                             : make_float4(0.f, 0.f, 0.f, 0.f);
            } else {
                av = *(const float4*)(A + (size_t)(bm0 + lrow) * lda + (size_t)kt1 * 8 + lk);
                wv = (n < N) ? *(const float4*)(W + (size_t)n * ldw + (size_t)kt1 * 8 + lk)
                             : make_float4(0.f, 0.f, 0.f, 0.f);
            }
        }
        #pragma unroll
        for (int k = 0; k < 8; ++k) {
            float a[8], b[8];
            #pragma unroll
            for (int i = 0; i < 8; ++i) a[i] = As[k][ty + 16 * i];
            #pragma unroll
            for (int j = 0; j < 8; ++j) b[j] = Bs[k][tx + 16 * j];
            #pragma unroll
            for (int i = 0; i < 8; ++i)
                #pragma unroll
                for (int j = 0; j < 8; ++j)
                    acc[i][j] = fmaf(a[i], b[j], acc[i][j]);
        }
    }
    #pragma unroll
    for (int i = 0; i < 8; ++i) {
        int m = bm0 + ty + 16 * i;
        #pragma unroll
        for (int j = 0; j < 8; ++j) {
            int n = bn0 + tx + 16 * j;
            if (n < N) {
                float v = acc[i][j];
                if (EPI == 2) v = softplusf(v + bias[n]);
                C[(size_t)m * ldc + n] = v;
            }
        }
    }
}

// ---- reduce split-K partials: out[i] = sum_sk part[sk*stride + i] ----
__global__ __launch_bounds__(256) void sk_reduce_kernel(
        const float* __restrict__ part, float* __restrict__ out, int total) {
    int i = blockIdx.x * 256 + threadIdx.x;
    if (i >= total) return;
    float s = 0.f;
    #pragma unroll
    for (int sk = 0; sk < SKX; ++sk) s += part[(size_t)sk * total + i];
    out[i] = s;
}

// ---- depthwise causal conv(4) + bias + SiLU ----
__global__ __launch_bounds__(256) void conv_silu_kernel(
        const float* __restrict__ xz, const float* __restrict__ cw,
        const float* __restrict__ cb, float* __restrict__ u) {
    int idx = blockIdx.x * 256 + threadIdx.x;
    int d  = idx & (D_INNER - 1);
    int bl = idx >> 11;
    int l  = bl & (SEQLEN - 1);
    const float* base = xz + (size_t)bl * 4096 + d;
    float4 w = *(const float4*)(cw + d * 4);
    float s = cb[d];
    if (l >= 3) s = fmaf(base[-3 * 4096], w.x, s);
    if (l >= 2) s = fmaf(base[-2 * 4096], w.y, s);
    if (l >= 1) s = fmaf(base[-1 * 4096], w.z, s);
    s = fmaf(base[0], w.w, s);
    u[idx] = s * (1.f / (1.f + __expf(-s)));
}

// ================= chunk-parallel selective scan =================
// Pass A: per-segment local scan from h=0. Stores hF[seg][row][16], sumd[seg][row].
__global__ __launch_bounds__(256) void scan_partA(
        const float* __restrict__ delta, const float* __restrict__ u,
        const float* __restrict__ xdbl, const float* __restrict__ A_log,
        float* __restrict__ hF, float* __restrict__ sumd) {
    const int tid = threadIdx.x;
    const int n = tid & 15;
    const int grp = tid >> 4;
    const int blk = blockIdx.x;          // 0..2047
    const int seg = blk >> 8;
    const int row = (blk & 255) * 16 + grp;
    const int b = row >> 11;
    const int d = row & (D_INNER - 1);
    const int t0 = seg * TSEG;
    const float An = -__expf(A_log[d * 16 + n]);
    const float* dl = delta + ((size_t)b * SEQLEN + t0) * D_INNER + d;
    const float* uu = u     + ((size_t)b * SEQLEN + t0) * D_INNER + d;
    const float* bc = xdbl  + ((size_t)b * SEQLEN + t0) * 96;
    float h = 0.f, sd = 0.f;
    float dv[4], uv[4], Bn[4];
    #pragma unroll
    for (int j = 0; j < 4; ++j) {
        dv[j] = dl[(size_t)j * D_INNER];
        uv[j] = uu[(size_t)j * D_INNER];
        Bn[j] = bc[(size_t)j * 96 + 64 + n];
    }
    for (int t4 = 0; t4 < TSEG; t4 += 4) {
        float nd[4], nu[4], nB[4];
        if (t4 + 4 < TSEG) {
            #pragma unroll
            for (int j = 0; j < 4; ++j) {
                size_t o = (size_t)(t4 + 4 + j);
                nd[j] = dl[o * D_INNER];
                nu[j] = uu[o * D_INNER];
                nB[j] = bc[o * 96 + 64 + n];
            }
        } else {
            #pragma unroll
            for (int j = 0; j < 4; ++j) { nd[j] = 0.f; nu[j] = 0.f; nB[j] = 0.f; }
        }
        #pragma unroll
        for (int j = 0; j < 4; ++j) {
            float dA = __expf(dv[j] * An);
            h = fmaf(dA, h, dv[j] * uv[j] * Bn[j]);
            sd += dv[j];
        }
        #pragma unroll
        for (int j = 0; j < 4; ++j) { dv[j] = nd[j]; uv[j] = nu[j]; Bn[j] = nB[j]; }
    }
    hF[((size_t)seg * (BATCH * D_INNER) + row) * 16 + n] = h;
    if (n == 0) sumd[(size_t)seg * (BATCH * D_INNER) + row] = sd;
}

// Combine: tiny sequential pass over NSEG segments per (row, n).
__global__ __launch_bounds__(256) void scan_combine(
        const float* __restrict__ A_log, const float* __restrict__ hF,
        const float* __restrict__ sumd, float* __restrict__ hin) {
    int idx = blockIdx.x * 256 + threadIdx.x;   // row*16 + n
    int n = idx & 15, row = idx >> 4;
    int d = row & (D_INNER - 1);
    float An = -__expf(A_log[d * 16 + n]);
    float h = 0.f;
    for (int s = 0; s < NSEG; ++s) {
        size_t o = (size_t)s * (BATCH * D_INNER) + row;
        hin[o * 16 + n] = h;
        h = fmaf(__expf(An * sumd[o]), h, hF[o * 16 + n]);
    }
}

// Pass B: re-scan each segment from hin, emit y*silu(z). yg may alias delta.
__global__ __launch_bounds__(256) void scan_partB(
        const float* __restrict__ delta, const float* __restrict__ u,
        const float* __restrict__ xdbl, const float* __restrict__ xz,
        const float* __restrict__ A_log, const float* __restrict__ Dp,
        const float* __restrict__ hin, float* __restrict__ yg) {
    const int tid = threadIdx.x;
    const int n = tid & 15;
    const int grp = tid >> 4;
    const int blk = blockIdx.x;
    const int seg = blk >> 8;
    const int row = (blk & 255) * 16 + grp;
    const int b = row >> 11;
    const int d = row & (D_INNER - 1);
    const int t0 = seg * TSEG;
    const float An = -__expf(A_log[d * 16 + n]);
    const float Dd = Dp[d];
    const float* dl = delta + ((size_t)b * SEQLEN + t0) * D_INNER + d;
    const float* uu = u     + ((size_t)b * SEQLEN + t0) * D_INNER + d;
    const float* bc = xdbl  + ((size_t)b * SEQLEN + t0) * 96;
    const float* zz = xz    + ((size_t)b * SEQLEN + t0) * 4096 + D_INNER + d;
    float* yo = yg + ((size_t)b * SEQLEN + t0) * D_INNER + d;
    float h = hin[((size_t)seg * (BATCH * D_INNER) + row) * 16 + n];
    float dv[4], uv[4], Bn[4], Cn[4], zv[4];
    #pragma unroll
    for (int j = 0; j < 4; ++j) {
        size_t o = (size_t)j;
        dv[j] = dl[o * D_INNER];
        uv[j] = uu[o * D_INNER];
        Bn[j] = bc[o * 96 + 64 + n];
        Cn[j] = bc[o * 96 + 80 + n];
        zv[j] = zz[o * 4096];
    }
    for (int t4 = 0; t4 < TSEG; t4 += 4) {
        float nd[4], nu[4], nB[4], nC[4], nz[4];
        if (t4 + 4 < TSEG) {
            #pragma unroll
            for (int j = 0; j < 4; ++j) {
                size_t o = (size_t)(t4 + 4 + j);
                nd[j] = dl[o * D_INNER];
                nu[j] = uu[o * D_INNER];
                nB[j] = bc[o * 96 + 64 + n];
                nC[j] = bc[o * 96 + 80 + n];
                nz[j] = zz[o * 4096];
            }
        } else {
            #pragma unroll
            for (int j = 0; j < 4; ++j) { nd[j]=0.f; nu[j]=0.f; nB[j]=0.f; nC[j]=0.f; nz[j]=0.f; }
        }
        #pragma unroll
        for (int j = 0; j < 4; ++j) {
            float dA = __expf(dv[j] * An);
            h = fmaf(dA, h, dv[j] * uv[j] * Bn[j]);
            float p = h * Cn[j];
            #pragma unroll
            for (int o2 = 8; o2; o2 >>= 1) p += __shfl_xor(p, o2, 16);
            if (n == 0) {
                float yv = fmaf(uv[j], Dd, p);
                yo[(size_t)(t4 + j) * D_INNER] = yv * (zv[j] / (1.f + __expf(-zv[j])));
            }
        }
        #pragma unroll
        for (int j = 0; j < 4; ++j) { dv[j]=nd[j]; uv[j]=nu[j]; Bn[j]=nB[j]; Cn[j]=nC[j]; zv[j]=nz[j]; }
    }
}

extern "C" void kernel_launch(void* const* d_in, const int* in_sizes, int n_in,
                              void* d_out, int out_size, void* d_ws, size_t ws_size,
                              hipStream_t stream) {
    const float* x        = (const float*)d_in[0];
    const float* w_in     = (const float*)d_in[1];
    const float* lA_in    = (const float*)d_in[2];
    const float* lB_in    = (const float*)d_in[3];
    const float* mask_in  = (const float*)d_in[4];
    const float* conv_w   = (const float*)d_in[5];
    const float* conv_b   = (const float*)d_in[6];
    const float* w_xp     = (const float*)d_in[7];
    const float* w_dt     = (const float*)d_in[8];
    const float* b_dt     = (const float*)d_in[9];
    const float* A_log    = (const float*)d_in[10];
    const float* Dp       = (const float*)d_in[11];
    const float* w_out    = (const float*)d_in[12];
    const float* lA_out   = (const float*)d_in[13];
    const float* lB_out   = (const float*)d_in[14];
    const float* mask_out = (const float*)d_in[15];

    // Workspace layout (floats). Total ≈ 130 MB.
    float* ws    = (float*)d_ws;
    float* xz    = ws;                              // [BL,4096]
    float* u     = xz    + (size_t)BL * 4096;       // [BL,2048]
    float* delta = u     + (size_t)BL * D_INNER;    // [BL,2048] (also yg)
    float* xdbl  = delta + (size_t)BL * D_INNER;    // [BL,96]
    float* t16   = xdbl  + (size_t)BL * 96;         // [BL,16]
    float* lbin  = t16   + (size_t)BL * 16;         // [4096,16]
    float* lbout = lbin  + (size_t)4096 * 16;       // [1024,16]

    // d_out (4M floats) doubles as pre-epilogue scratch; all uses complete
    // before the final out_proj GEMM overwrites it.
    float* outf    = (float*)d_out;
    float* xp_part = outf;                                   // [SKX][BL*96] = 3.15M
    float* hF      = outf;                                   // [NSEG][4096][16] = 0.52M (after xp consumed)
    float* hin     = hF + (size_t)NSEG * BL * 16;            // 0.52M
    float* sumd    = hin + (size_t)NSEG * BL * 16;           // 32K

    // 1) LoRA premultiply
    premul_kernel<<<(4096 * 16 + 255) / 256, 256, 0, stream>>>(lB_in, mask_in, lbin, 4096 * 16);
    premul_kernel<<<(1024 * 16 + 255) / 256, 256, 0, stream>>>(lB_out, mask_out, lbout, 1024 * 16);
    // 2) t16 = x @ lora_A_in^T
    lora_t_kernel<<<BL, 256, 0, stream>>>(x, D_MODEL, lA_in, D_MODEL, t16);
    // 3) xz = x @ w_in^T + LoRA
    gemm_kernel<1><<<dim3(4096 / 128, BL / 128), 256, 0, stream>>>(
        x, D_MODEL, w_in, D_MODEL, xz, 4096, BL, 4096, D_MODEL, 0, t16, lbin, nullptr);
    // 4) u = silu(conv(xs) + b)
    conv_silu_kernel<<<(BL * D_INNER) / 256, 256, 0, stream>>>(xz, conv_w, conv_b, u);
    // 5) x_proj split-K: partials then reduce
    gemm_kernel<0><<<dim3(1, BL / 128, SKX), 256, 0, stream>>>(
        u, D_INNER, w_xp, D_INNER, xp_part, 96, BL, 96, KCH, KCH, nullptr, nullptr, nullptr);
    sk_reduce_kernel<<<(BL * 96 + 255) / 256, 256, 0, stream>>>(xp_part, xdbl, BL * 96);
    // 6) delta = softplus(dt @ w_dt^T + b_dt)
    gemm_kernel<2><<<dim3(D_INNER / 128, BL / 128), 256, 0, stream>>>(
        xdbl, 96, w_dt, DTRANK, delta, D_INNER, BL, D_INNER, DTRANK, 0, nullptr, nullptr, b_dt);
    // 7) chunk-parallel selective scan (+ gating); yg aliases delta
    scan_partA<<<NSEG * 256, 256, 0, stream>>>(delta, u, xdbl, A_log, hF, sumd);
    scan_combine<<<(BATCH * D_INNER * 16) / 256, 256, 0, stream>>>(A_log, hF, sumd, hin);
    scan_partB<<<NSEG * 256, 256, 0, stream>>>(delta, u, xdbl, xz, A_log, Dp, hin, delta);
    // 8) t16 = yg @ lora_A_out^T
    lora_t_kernel<<<BL, 256, 0, stream>>>(delta, D_INNER, lA_out, D_MODEL + D_INNER - D_MODEL /*=D_INNER*/, t16);
    // 9) out = yg @ w_out^T + LoRA
    gemm_kernel<1><<<dim3(D_MODEL / 128, BL / 128), 256, 0, stream>>>(
        delta, D_INNER, w_out, D_INNER, (float*)d_out, D_MODEL, BL, D_MODEL, D_INNER, 0, t16, lbout, nullptr);
}

// Round 3
// 696.093 us; speedup vs baseline: 3.0553x; 1.8236x over previous
//
#include <hip/hip_runtime.h>
#include <hip/hip_bf16.h>
#include <cstdint>
#include <cstddef>

// Problem constants (from reference)
#define D_MODEL 1024
#define D_INNER 2048
#define NSTATE  16
#define DTRANK  64
#define BATCH   2
#define SEQLEN  2048
#define BL      (BATCH*SEQLEN)   // 4096 tokens
#define NSEG    8
#define TSEG    (SEQLEN/NSEG)    // 256
#define SKX     8                // split-K factor for x_proj
#define KCH     (D_INNER/SKX)    // 256

typedef __attribute__((ext_vector_type(8))) short s16x8;
typedef __attribute__((ext_vector_type(4))) float f32x4;

__device__ __forceinline__ float softplusf(float x) {
    return fmaxf(x, 0.f) + log1pf(expf(-fabsf(x)));
}
__device__ __forceinline__ unsigned short f2bf(float x) {
    __hip_bfloat16 b = __float2bfloat16(x);
    return *(unsigned short*)&b;
}
__device__ __forceinline__ float bf2f(unsigned short u) {
    __hip_bfloat16 b; *(unsigned short*)&b = u;
    return __bfloat162float(b);
}

// ---- lbp[n,r] = lora_B[n,r] * mask[n] * 2.0 ----
__global__ __launch_bounds__(256) void premul_kernel(
        const float* __restrict__ lb, const float* __restrict__ mask,
        float* __restrict__ out, int total) {
    int i = blockIdx.x * 256 + threadIdx.x;
    if (i < total) out[i] = lb[i] * mask[i >> 4] * 2.0f;
}

// ---- T[m,r] = sum_k X[m,k] * LA[r,k]   (r < 16) ----
__global__ __launch_bounds__(256) void lora_t_kernel(
        const float* __restrict__ X, int ldx,
        const float* __restrict__ LA, int K,
        float* __restrict__ T) {
    int m = blockIdx.x;
    int r = threadIdx.x >> 4;
    int l = threadIdx.x & 15;
    const float* xrow = X + (size_t)m * ldx;
    const float* arow = LA + (size_t)r * K;
    float s = 0.f;
    for (int k = 4 * l; k < K; k += 64) {
        float4 xv = *(const float4*)(xrow + k);
        float4 av = *(const float4*)(arow + k);
        s += xv.x * av.x + xv.y * av.y + xv.z * av.z + xv.w * av.w;
    }
    #pragma unroll
    for (int o = 8; o; o >>= 1) s += __shfl_xor(s, o, 16);
    if (l == 0) T[(size_t)m * 16 + r] = s;
}

// ---- hi/lo bf16 split of an f32 matrix: hi=bf16(v), lo=bf16(v-hi) ----
// src [M][lda] f32, writes hi/lo [M][KP] over the first K columns.
__global__ __launch_bounds__(256) void hilo_kernel(
        const float* __restrict__ src, int lda, int K4, int KP,
        unsigned short* __restrict__ hi, unsigned short* __restrict__ lo,
        int total4) {
    int idx = blockIdx.x * 256 + threadIdx.x;
    if (idx >= total4) return;
    int m = idx / K4;
    int kq = idx - m * K4;
    float4 v = *(const float4*)(src + (size_t)m * lda + kq * 4);
    ushort4 h, l;
    h.x = f2bf(v.x); l.x = f2bf(v.x - bf2f(h.x));
    h.y = f2bf(v.y); l.y = f2bf(v.y - bf2f(h.y));
    h.z = f2bf(v.z); l.z = f2bf(v.z - bf2f(h.z));
    h.w = f2bf(v.w); l.w = f2bf(v.w - bf2f(h.w));
    *(ushort4*)(hi + (size_t)m * KP + kq * 4) = h;
    *(ushort4*)(lo + (size_t)m * KP + kq * 4) = l;
}

// ---- LoRA K-extension: cols [K,K+16) = bf16(t16[m][r]) in hi, 0 in lo;
//      cols [K+16,K+32) = 0 in both. ----
__global__ __launch_bounds__(256) void ext_kernel(
        const float* __restrict__ t16, int K, int KP,
        unsigned short* __restrict__ hi, unsigned short* __restrict__ lo,
        int M) {
    int idx = blockIdx.x * 256 + threadIdx.x;
    if (idx >= M * 32) return;
    int c = idx & 31, m = idx >> 5;
    unsigned short hv = 0;
    if (c < 16) hv = f2bf(t16[(size_t)m * 16 + c]);
    hi[(size_t)m * KP + K + c] = hv;
    lo[(size_t)m * KP + K + c] = 0;
}

// ---- hi/lo bf16 MFMA GEMM: C[m,n] = sum_k A[m,k]*W[n,k] (fp32-quality) ----
// 128x128 tile, BK=32, 4 waves of 64x64, 16x16x32 bf16 MFMA, 3 passes
// (Ah*Wh + Ah*Wl + Al*Wh). LDS in kg-split [4][128][8] layout ->
// conflict-free ds_read_b128. EPI==0 plain, EPI==2 softplus(v+bias[n]).
template<int EPI>
__global__ __launch_bounds__(256, 2) void mfma_gemm(
        const unsigned short* __restrict__ Ahg, const unsigned short* __restrict__ Alg,
        const unsigned short* __restrict__ Whg, const unsigned short* __restrict__ Wlg,
        int KP, float* __restrict__ C, int ldc,
        const float* __restrict__ bias) {
    __shared__ short Ash[4][128][8];
    __shared__ short Asl[4][128][8];
    __shared__ short Wsh[4][128][8];
    __shared__ short Wsl[4][128][8];
    const int tid = threadIdx.x;
    const int bn0 = blockIdx.x * 128, bm0 = blockIdx.y * 128;
    const int wave = tid >> 6, lane = tid & 63;
    const int wr = (wave >> 1) * 64, wc = (wave & 1) * 64;
    const int fr = lane & 15, fg = lane >> 4;
    const int KT = KP >> 5;
    // staging: thread handles 16B chunks j0=tid (row=tid&127, kg=tid>>7) and
    // j1=tid+256 (same row, kg+2).
    const int srow = tid & 127, skg = tid >> 7;

    const unsigned short* pAh = Ahg + (size_t)(bm0 + srow) * KP + skg * 8;
    const unsigned short* pAl = Alg + (size_t)(bm0 + srow) * KP + skg * 8;
    const unsigned short* pWh = Whg + (size_t)(bn0 + srow) * KP + skg * 8;
    const unsigned short* pWl = Wlg + (size_t)(bn0 + srow) * KP + skg * 8;

    f32x4 acc[4][4];
    #pragma unroll
    for (int i = 0; i < 4; ++i)
        #pragma unroll
        for (int j = 0; j < 4; ++j) acc[i][j] = (f32x4){0.f, 0.f, 0.f, 0.f};

    for (int kt = 0; kt < KT; ++kt) {
        const int koff = kt * 32;
        s16x8 vah0 = *(const s16x8*)(pAh + koff);
        s16x8 vah1 = *(const s16x8*)(pAh + koff + 16);
        s16x8 val0 = *(const s16x8*)(pAl + koff);
        s16x8 val1 = *(const s16x8*)(pAl + koff + 16);
        s16x8 vwh0 = *(const s16x8*)(pWh + koff);
        s16x8 vwh1 = *(const s16x8*)(pWh + koff + 16);
        s16x8 vwl0 = *(const s16x8*)(pWl + koff);
        s16x8 vwl1 = *(const s16x8*)(pWl + koff + 16);
        __syncthreads();   // previous tile fully consumed
        *(s16x8*)&Ash[skg    ][srow][0] = vah0;
        *(s16x8*)&Ash[skg + 2][srow][0] = vah1;
        *(s16x8*)&Asl[skg    ][srow][0] = val0;
        *(s16x8*)&Asl[skg + 2][srow][0] = val1;
        *(s16x8*)&Wsh[skg    ][srow][0] = vwh0;
        *(s16x8*)&Wsh[skg + 2][srow][0] = vwh1;
        *(s16x8*)&Wsl[skg    ][srow][0] = vwl0;
        *(s16x8*)&Wsl[skg + 2][srow][0] = vwl1;
        __syncthreads();
        s16x8 ah[4], al[4], wh[4], wl[4];
        #pragma unroll
        for (int i = 0; i < 4; ++i) {
            ah[i] = *(const s16x8*)&Ash[fg][wr + i * 16 + fr][0];
            al[i] = *(const s16x8*)&Asl[fg][wr + i * 16 + fr][0];
            wh[i] = *(const s16x8*)&Wsh[fg][wc + i * 16 + fr][0];
            wl[i] = *(const s16x8*)&Wsl[fg][wc + i * 16 + fr][0];
        }
        #pragma unroll
        for (int i = 0; i < 4; ++i)
            #pragma unroll
            for (int j = 0; j < 4; ++j) {
                acc[i][j] = __builtin_amdgcn_mfma_f32_16x16x32_bf16(ah[i], wh[j], acc[i][j], 0, 0, 0);
                acc[i][j] = __builtin_amdgcn_mfma_f32_16x16x32_bf16(ah[i], wl[j], acc[i][j], 0, 0, 0);
                acc[i][j] = __builtin_amdgcn_mfma_f32_16x16x32_bf16(al[i], wh[j], acc[i][j], 0, 0, 0);
            }
    }
    // C/D layout: col = lane&15, row = (lane>>4)*4 + q   [m89-verified]
    #pragma unroll
    for (int i = 0; i < 4; ++i) {
        #pragma unroll
        for (int j = 0; j < 4; ++j) {
            int n = bn0 + wc + j * 16 + fr;
            #pragma unroll
            for (int q = 0; q < 4; ++q) {
                int m = bm0 + wr + i * 16 + fg * 4 + q;
                float v = acc[i][j][q];
                if (EPI == 2) v = softplusf(v + bias[n]);
                C[(size_t)m * ldc + n] = v;
            }
        }
    }
}

// ---- fp32 tiled GEMM (kept for x_proj split-K; N=96 too small for MFMA tile)
__global__ __launch_bounds__(256) void gemm_f32_kernel(
        const float* __restrict__ A, int lda,
        const float* __restrict__ W, int ldw,
        float* __restrict__ C, int ldc,
        int M, int N, int K, int kchunk) {
    __shared__ float As[8][128];
    __shared__ float Bs[8][128];
    if (kchunk) {
        A += (size_t)blockIdx.z * kchunk;
        W += (size_t)blockIdx.z * kchunk;
        C += (size_t)blockIdx.z * M * ldc;
    }
    const int tid = threadIdx.x;
    const int tx = tid & 15, ty = tid >> 4;
    const int bn0 = blockIdx.x * 128, bm0 = blockIdx.y * 128;
    const int lrow = tid >> 1;
    const int lk   = (tid & 1) * 4;
    const int nk = K >> 3;

    float acc[8][8];
    #pragma unroll
    for (int i = 0; i < 8; ++i)
        #pragma unroll
        for (int j = 0; j < 8; ++j) acc[i][j] = 0.f;

    float4 av, wv;
    {
        av = *(const float4*)(A + (size_t)(bm0 + lrow) * lda + lk);
        int n = bn0 + lrow;
        wv = (n < N) ? *(const float4*)(W + (size_t)n * ldw + lk)
                     : make_float4(0.f, 0.f, 0.f, 0.f);
    }
    for (int kt = 0; kt < nk; ++kt) {
        __syncthreads();
        As[lk + 0][lrow] = av.x; As[lk + 1][lrow] = av.y;
        As[lk + 2][lrow] = av.z; As[lk + 3][lrow] = av.w;
        Bs[lk + 0][lrow] = wv.x; Bs[lk + 1][lrow] = wv.y;
        Bs[lk + 2][lrow] = wv.z; Bs[lk + 3][lrow] = wv.w;
        __syncthreads();
        int kt1 = kt + 1;
        if (kt1 < nk) {
            int n = bn0 + lrow;
            av = *(const float4*)(A + (size_t)(bm0 + lrow) * lda + (size_t)kt1 * 8 + lk);
            wv = (n < N) ? *(const float4*)(W + (size_t)n * ldw + (size_t)kt1 * 8 + lk)
                         : make_float4(0.f, 0.f, 0.f, 0.f);
        }
        #pragma unroll
        for (int k = 0; k < 8; ++k) {
            float a[8], b[8];
            #pragma unroll
            for (int i = 0; i < 8; ++i) a[i] = As[k][ty + 16 * i];
            #pragma unroll
            for (int j = 0; j < 8; ++j) b[j] = Bs[k][tx + 16 * j];
            #pragma unroll
            for (int i = 0; i < 8; ++i)
                #pragma unroll
                for (int j = 0; j < 8; ++j)
                    acc[i][j] = fmaf(a[i], b[j], acc[i][j]);
        }
    }
    #pragma unroll
    for (int i = 0; i < 8; ++i) {
        int m = bm0 + ty + 16 * i;
        #pragma unroll
        for (int j = 0; j < 8; ++j) {
            int n = bn0 + tx + 16 * j;
            if (n < N) C[(size_t)m * ldc + n] = acc[i][j];
        }
    }
}

// ---- reduce split-K partials ----
__global__ __launch_bounds__(256) void sk_reduce_kernel(
        const float* __restrict__ part, float* __restrict__ out, int total) {
    int i = blockIdx.x * 256 + threadIdx.x;
    if (i >= total) return;
    float s = 0.f;
    #pragma unroll
    for (int sk = 0; sk < SKX; ++sk) s += part[(size_t)sk * total + i];
    out[i] = s;
}

// ---- depthwise causal conv(4) + bias + SiLU ----
__global__ __launch_bounds__(256) void conv_silu_kernel(
        const float* __restrict__ xz, const float* __restrict__ cw,
        const float* __restrict__ cb, float* __restrict__ u) {
    int idx = blockIdx.x * 256 + threadIdx.x;
    int d  = idx & (D_INNER - 1);
    int bl = idx >> 11;
    int l  = bl & (SEQLEN - 1);
    const float* base = xz + (size_t)bl * 4096 + d;
    float4 w = *(const float4*)(cw + d * 4);
    float s = cb[d];
    if (l >= 3) s = fmaf(base[-3 * 4096], w.x, s);
    if (l >= 2) s = fmaf(base[-2 * 4096], w.y, s);
    if (l >= 1) s = fmaf(base[-1 * 4096], w.z, s);
    s = fmaf(base[0], w.w, s);
    u[idx] = s * (1.f / (1.f + __expf(-s)));
}

// ================= chunk-parallel selective scan =================
__global__ __launch_bounds__(256) void scan_partA(
        const float* __restrict__ delta, const float* __restrict__ u,
        const float* __restrict__ xdbl, const float* __restrict__ A_log,
        float* __restrict__ hF, float* __restrict__ sumd) {
    const int tid = threadIdx.x;
    const int n = tid & 15;
    const int grp = tid >> 4;
    const int blk = blockIdx.x;
    const int seg = blk >> 8;
    const int row = (blk & 255) * 16 + grp;
    const int b = row >> 11;
    const int d = row & (D_INNER - 1);
    const int t0 = seg * TSEG;
    const float An = -__expf(A_log[d * 16 + n]);
    const float* dl = delta + ((size_t)b * SEQLEN + t0) * D_INNER + d;
    const float* uu = u     + ((size_t)b * SEQLEN + t0) * D_INNER + d;
    const float* bc = xdbl  + ((size_t)b * SEQLEN + t0) * 96;
    float h = 0.f, sd = 0.f;
    float dv[4], uv[4], Bn[4];
    #pragma unroll
    for (int j = 0; j < 4; ++j) {
        dv[j] = dl[(size_t)j * D_INNER];
        uv[j] = uu[(size_t)j * D_INNER];
        Bn[j] = bc[(size_t)j * 96 + 64 + n];
    }
    for (int t4 = 0; t4 < TSEG; t4 += 4) {
        float nd[4], nu[4], nB[4];
        if (t4 + 4 < TSEG) {
            #pragma unroll
            for (int j = 0; j < 4; ++j) {
                size_t o = (size_t)(t4 + 4 + j);
                nd[j] = dl[o * D_INNER];
                nu[j] = uu[o * D_INNER];
                nB[j] = bc[o * 96 + 64 + n];
            }
        } else {
            #pragma unroll
            for (int j = 0; j < 4; ++j) { nd[j] = 0.f; nu[j] = 0.f; nB[j] = 0.f; }
        }
        #pragma unroll
        for (int j = 0; j < 4; ++j) {
            float dA = __expf(dv[j] * An);
            h = fmaf(dA, h, dv[j] * uv[j] * Bn[j]);
            sd += dv[j];
        }
        #pragma unroll
        for (int j = 0; j < 4; ++j) { dv[j] = nd[j]; uv[j] = nu[j]; Bn[j] = nB[j]; }
    }
    hF[((size_t)seg * (BATCH * D_INNER) + row) * 16 + n] = h;
    if (n == 0) sumd[(size_t)seg * (BATCH * D_INNER) + row] = sd;
}

__global__ __launch_bounds__(256) void scan_combine(
        const float* __restrict__ A_log, const float* __restrict__ hF,
        const float* __restrict__ sumd, float* __restrict__ hin) {
    int idx = blockIdx.x * 256 + threadIdx.x;
    int n = idx & 15, row = idx >> 4;
    int d = row & (D_INNER - 1);
    float An = -__expf(A_log[d * 16 + n]);
    float h = 0.f;
    for (int s = 0; s < NSEG; ++s) {
        size_t o = (size_t)s * (BATCH * D_INNER) + row;
        hin[o * 16 + n] = h;
        h = fmaf(__expf(An * sumd[o]), h, hF[o * 16 + n]);
    }
}

__global__ __launch_bounds__(256) void scan_partB(
        const float* __restrict__ delta, const float* __restrict__ u,
        const float* __restrict__ xdbl, const float* __restrict__ xz,
        const float* __restrict__ A_log, const float* __restrict__ Dp,
        const float* __restrict__ hin, float* __restrict__ yg) {
    const int tid = threadIdx.x;
    const int n = tid & 15;
    const int grp = tid >> 4;
    const int blk = blockIdx.x;
    const int seg = blk >> 8;
    const int row = (blk & 255) * 16 + grp;
    const int b = row >> 11;
    const int d = row & (D_INNER - 1);
    const int t0 = seg * TSEG;
    const float An = -__expf(A_log[d * 16 + n]);
    const float Dd = Dp[d];
    const float* dl = delta + ((size_t)b * SEQLEN + t0) * D_INNER + d;
    const float* uu = u     + ((size_t)b * SEQLEN + t0) * D_INNER + d;
    const float* bc = xdbl  + ((size_t)b * SEQLEN + t0) * 96;
    const float* zz = xz    + ((size_t)b * SEQLEN + t0) * 4096 + D_INNER + d;
    float* yo = yg + ((size_t)b * SEQLEN + t0) * D_INNER + d;
    float h = hin[((size_t)seg * (BATCH * D_INNER) + row) * 16 + n];
    float dv[4], uv[4], Bn[4], Cn[4], zv[4];
    #pragma unroll
    for (int j = 0; j < 4; ++j) {
        size_t o = (size_t)j;
        dv[j] = dl[o * D_INNER];
        uv[j] = uu[o * D_INNER];
        Bn[j] = bc[o * 96 + 64 + n];
        Cn[j] = bc[o * 96 + 80 + n];
        zv[j] = zz[o * 4096];
    }
    for (int t4 = 0; t4 < TSEG; t4 += 4) {
        float nd[4], nu[4], nB[4], nC[4], nz[4];
        if (t4 + 4 < TSEG) {
            #pragma unroll
            for (int j = 0; j < 4; ++j) {
                size_t o = (size_t)(t4 + 4 + j);
                nd[j] = dl[o * D_INNER];
                nu[j] = uu[o * D_INNER];
                nB[j] = bc[o * 96 + 64 + n];
                nC[j] = bc[o * 96 + 80 + n];
                nz[j] = zz[o * 4096];
            }
        } else {
            #pragma unroll
            for (int j = 0; j < 4; ++j) { nd[j]=0.f; nu[j]=0.f; nB[j]=0.f; nC[j]=0.f; nz[j]=0.f; }
        }
        #pragma unroll
        for (int j = 0; j < 4; ++j) {
            float dA = __expf(dv[j] * An);
            h = fmaf(dA, h, dv[j] * uv[j] * Bn[j]);
            float p = h * Cn[j];
            #pragma unroll
            for (int o2 = 8; o2; o2 >>= 1) p += __shfl_xor(p, o2, 16);
            if (n == 0) {
                float yv = fmaf(uv[j], Dd, p);
                yo[(size_t)(t4 + j) * D_INNER] = yv * (zv[j] / (1.f + __expf(-zv[j])));
            }
        }
        #pragma unroll
        for (int j = 0; j < 4; ++j) { dv[j]=nd[j]; uv[j]=nu[j]; Bn[j]=nB[j]; Cn[j]=nC[j]; zv[j]=nz[j]; }
    }
}

extern "C" void kernel_launch(void* const* d_in, const int* in_sizes, int n_in,
                              void* d_out, int out_size, void* d_ws, size_t ws_size,
                              hipStream_t stream) {
    const float* x        = (const float*)d_in[0];
    const float* w_in     = (const float*)d_in[1];
    const float* lA_in    = (const float*)d_in[2];
    const float* lB_in    = (const float*)d_in[3];
    const float* mask_in  = (const float*)d_in[4];
    const float* conv_w   = (const float*)d_in[5];
    const float* conv_b   = (const float*)d_in[6];
    const float* w_xp     = (const float*)d_in[7];
    const float* w_dt     = (const float*)d_in[8];
    const float* b_dt     = (const float*)d_in[9];
    const float* A_log    = (const float*)d_in[10];
    const float* Dp       = (const float*)d_in[11];
    const float* w_out    = (const float*)d_in[12];
    const float* lA_out   = (const float*)d_in[13];
    const float* lB_out   = (const float*)d_in[14];
    const float* mask_out = (const float*)d_in[15];

    // f32 workspace layout (same footprint as round 2)
    float* ws    = (float*)d_ws;
    float* xz    = ws;                              // [BL,4096]
    float* u     = xz    + (size_t)BL * 4096;       // [BL,2048]
    float* delta = u     + (size_t)BL * D_INNER;    // [BL,2048] (also yg)
    float* xdbl  = delta + (size_t)BL * D_INNER;    // [BL,96]
    float* t16   = xdbl  + (size_t)BL * 96;         // [BL,16]
    float* lbin  = t16   + (size_t)BL * 16;         // [4096,16]
    float* lbout = lbin  + (size_t)4096 * 16;       // [1024,16]

    // bf16 arenas reuse DEAD f32 regions (no workspace growth):
    //  - in_proj bufs (34.6 MB) live in u+delta (written only later)
    //  - dt bufs (1.6 MB) live in d_out (xp_part consumed by then)
    //  - out_proj bufs (42.6 MB) live in xz (dead after scan_partB)
    const size_t AS_IN = (size_t)4096 * 1056, WS_IN = (size_t)4096 * 1056;
    unsigned short* Ahi_in = (unsigned short*)u;
    unsigned short* Alo_in = Ahi_in + AS_IN;
    unsigned short* Whi_in = Alo_in + AS_IN;
    unsigned short* Wlo_in = Whi_in + WS_IN;

    unsigned short* dtb = (unsigned short*)d_out;
    unsigned short* Ahi_dt = dtb;                       // 4096*64
    unsigned short* Alo_dt = Ahi_dt + (size_t)4096 * 64;
    unsigned short* Whi_dt = Alo_dt + (size_t)4096 * 64; // 2048*64
    unsigned short* Wlo_dt = Whi_dt + (size_t)2048 * 64;

    const size_t AS_OUT = (size_t)4096 * 2080, WS_OUT = (size_t)1024 * 2080;
    unsigned short* Ahi_out = (unsigned short*)xz;
    unsigned short* Alo_out = Ahi_out + AS_OUT;
    unsigned short* Whi_out = Alo_out + AS_OUT;
    unsigned short* Wlo_out = Whi_out + WS_OUT;

    // d_out f32 scratch (pre-final uses)
    float* outf    = (float*)d_out;
    float* xp_part = outf;                               // [SKX][BL*96]
    float* hF      = outf;                               // scan scratch (after dt bufs dead)
    float* hin     = hF + (size_t)NSEG * BL * 16;
    float* sumd    = hin + (size_t)NSEG * BL * 16;

    // 1) LoRA premultiply + t16_in
    premul_kernel<<<(4096 * 16 + 255) / 256, 256, 0, stream>>>(lB_in, mask_in, lbin, 4096 * 16);
    premul_kernel<<<(1024 * 16 + 255) / 256, 256, 0, stream>>>(lB_out, mask_out, lbout, 1024 * 16);
    lora_t_kernel<<<BL, 256, 0, stream>>>(x, D_MODEL, lA_in, D_MODEL, t16);
    // 2) hi/lo conversions for in_proj (K=1024, KP=1056 incl. LoRA ext)
    hilo_kernel<<<4096, 256, 0, stream>>>(x,    1024, 256, 1056, Ahi_in, Alo_in, 4096 * 256);
    hilo_kernel<<<4096, 256, 0, stream>>>(w_in, 1024, 256, 1056, Whi_in, Wlo_in, 4096 * 256);
    ext_kernel<<<512, 256, 0, stream>>>(t16,  1024, 1056, Ahi_in, Alo_in, 4096);
    ext_kernel<<<512, 256, 0, stream>>>(lbin, 1024, 1056, Whi_in, Wlo_in, 4096);
    // 3) in_proj MFMA GEMM -> xz
    mfma_gemm<0><<<dim3(32, 32), 256, 0, stream>>>(
        Ahi_in, Alo_in, Whi_in, Wlo_in, 1056, xz, 4096, nullptr);
    // 4) u = silu(conv(xs) + b)
    conv_silu_kernel<<<(BL * D_INNER) / 256, 256, 0, stream>>>(xz, conv_w, conv_b, u);
    // 5) x_proj split-K fp32 -> xdbl
    gemm_f32_kernel<<<dim3(1, BL / 128, SKX), 256, 0, stream>>>(
        u, D_INNER, w_xp, D_INNER, xp_part, 96, BL, 96, KCH, KCH);
    sk_reduce_kernel<<<(BL * 96 + 255) / 256, 256, 0, stream>>>(xp_part, xdbl, BL * 96);
    // 6) dt_proj MFMA (K=64, KP=64) -> delta = softplus(. + b_dt)
    hilo_kernel<<<(4096 * 16 + 255) / 256, 256, 0, stream>>>(xdbl, 96, 16, 64, Ahi_dt, Alo_dt, 4096 * 16);
    hilo_kernel<<<(2048 * 16 + 255) / 256, 256, 0, stream>>>(w_dt, 64, 16, 64, Whi_dt, Wlo_dt, 2048 * 16);
    mfma_gemm<2><<<dim3(16, 32), 256, 0, stream>>>(
        Ahi_dt, Alo_dt, Whi_dt, Wlo_dt, 64, delta, 2048, b_dt);
    // 7) chunk-parallel selective scan (+ gating); yg aliases delta
    scan_partA<<<NSEG * 256, 256, 0, stream>>>(delta, u, xdbl, A_log, hF, sumd);
    scan_combine<<<(BATCH * D_INNER * 16) / 256, 256, 0, stream>>>(A_log, hF, sumd, hin);
    scan_partB<<<NSEG * 256, 256, 0, stream>>>(delta, u, xdbl, xz, A_log, Dp, hin, delta);
    // 8) out_proj: t16_out, conversions (K=2048, KP=2080), MFMA -> d_out
    lora_t_kernel<<<BL, 256, 0, stream>>>(delta, D_INNER, lA_out, D_INNER, t16);
    hilo_kernel<<<8192, 256, 0, stream>>>(delta, 2048, 512, 2080, Ahi_out, Alo_out, 4096 * 512);
    hilo_kernel<<<2048, 256, 0, stream>>>(w_out, 2048, 512, 2080, Whi_out, Wlo_out, 1024 * 512);
    ext_kernel<<<512, 256, 0, stream>>>(t16,   2048, 2080, Ahi_out, Alo_out, 4096);
    ext_kernel<<<128, 256, 0, stream>>>(lbout, 2048, 2080, Whi_out, Wlo_out, 1024);
    mfma_gemm<0><<<dim3(8, 32), 256, 0, stream>>>(
        Ahi_out, Alo_out, Whi_out, Wlo_out, 2080, (float*)d_out, 1024, nullptr);
}

// Round 4
// 621.894 us; speedup vs baseline: 3.4198x; 1.1193x over previous
//
#include <hip/hip_runtime.h>
#include <hip/hip_bf16.h>
#include <cstdint>
#include <cstddef>

// Problem constants (from reference)
#define D_MODEL 1024
#define D_INNER 2048
#define NSTATE  16
#define DTRANK  64
#define BATCH   2
#define SEQLEN  2048
#define BL      (BATCH*SEQLEN)   // 4096 tokens
#define NSEG    32
#define TSEG    (SEQLEN/NSEG)    // 64
#define SKX     8                // split-K factor for x_proj
#define KCH     (D_INNER/SKX)    // 256
#define LOG2E   1.4426950408889634f

typedef __attribute__((ext_vector_type(8))) short s16x8;
typedef __attribute__((ext_vector_type(4))) float f32x4;

__device__ __forceinline__ float softplusf(float x) {
    return fmaxf(x, 0.f) + log1pf(expf(-fabsf(x)));
}
__device__ __forceinline__ unsigned short f2bf(float x) {
    __hip_bfloat16 b = __float2bfloat16(x);
    return *(unsigned short*)&b;
}
__device__ __forceinline__ float bf2f(unsigned short u) {
    __hip_bfloat16 b; *(unsigned short*)&b = u;
    return __bfloat162float(b);
}
// async global->LDS, 16B per lane (dest must be linear: base + lane*16)
__device__ __forceinline__ void gll16(const void* g, void* l) {
    __builtin_amdgcn_global_load_lds(
        (const __attribute__((address_space(1))) void*)g,
        (__attribute__((address_space(3))) void*)l, 16, 0, 0);
}

// ---- lbp[n,r] = lora_B[n,r] * mask[n] * 2.0 ----
__global__ __launch_bounds__(256) void premul_kernel(
        const float* __restrict__ lb, const float* __restrict__ mask,
        float* __restrict__ out, int total) {
    int i = blockIdx.x * 256 + threadIdx.x;
    if (i < total) out[i] = lb[i] * mask[i >> 4] * 2.0f;
}

// ---- T[m,r] = sum_k X[m,k] * LA[r,k]   (r < 16) ----
__global__ __launch_bounds__(256) void lora_t_kernel(
        const float* __restrict__ X, int ldx,
        const float* __restrict__ LA, int K,
        float* __restrict__ T) {
    int m = blockIdx.x;
    int r = threadIdx.x >> 4;
    int l = threadIdx.x & 15;
    const float* xrow = X + (size_t)m * ldx;
    const float* arow = LA + (size_t)r * K;
    float s = 0.f;
    for (int k = 4 * l; k < K; k += 64) {
        float4 xv = *(const float4*)(xrow + k);
        float4 av = *(const float4*)(arow + k);
        s += xv.x * av.x + xv.y * av.y + xv.z * av.z + xv.w * av.w;
    }
    #pragma unroll
    for (int o = 8; o; o >>= 1) s += __shfl_xor(s, o, 16);
    if (l == 0) T[(size_t)m * 16 + r] = s;
}

// ---- hi/lo bf16 split: hi=bf16(v), lo=bf16(v-hi) ----
__global__ __launch_bounds__(256) void hilo_kernel(
        const float* __restrict__ src, int lda, int K4, int KP,
        unsigned short* __restrict__ hi, unsigned short* __restrict__ lo,
        int total4) {
    int idx = blockIdx.x * 256 + threadIdx.x;
    if (idx >= total4) return;
    int m = idx / K4;
    int kq = idx - m * K4;
    float4 v = *(const float4*)(src + (size_t)m * lda + kq * 4);
    ushort4 h, l;
    h.x = f2bf(v.x); l.x = f2bf(v.x - bf2f(h.x));
    h.y = f2bf(v.y); l.y = f2bf(v.y - bf2f(h.y));
    h.z = f2bf(v.z); l.z = f2bf(v.z - bf2f(h.z));
    h.w = f2bf(v.w); l.w = f2bf(v.w - bf2f(h.w));
    *(ushort4*)(hi + (size_t)m * KP + kq * 4) = h;
    *(ushort4*)(lo + (size_t)m * KP + kq * 4) = l;
}

// ---- LoRA K-extension columns ----
__global__ __launch_bounds__(256) void ext_kernel(
        const float* __restrict__ t16, int K, int KP,
        unsigned short* __restrict__ hi, unsigned short* __restrict__ lo,
        int M) {
    int idx = blockIdx.x * 256 + threadIdx.x;
    if (idx >= M * 32) return;
    int c = idx & 31, m = idx >> 5;
    unsigned short hv = 0;
    if (c < 16) hv = f2bf(t16[(size_t)m * 16 + c]);
    hi[(size_t)m * KP + K + c] = hv;
    lo[(size_t)m * KP + K + c] = 0;
}

// ---- hi/lo bf16 MFMA GEMM, global_load_lds staging (m97 structure) ----
template<int EPI>
__global__ __launch_bounds__(256, 2) void mfma_gemm(
        const unsigned short* __restrict__ Ahg, const unsigned short* __restrict__ Alg,
        const unsigned short* __restrict__ Whg, const unsigned short* __restrict__ Wlg,
        int KP, float* __restrict__ C, int ldc,
        const float* __restrict__ bias) {
    __shared__ __align__(16) short Ash[4][128][8];
    __shared__ __align__(16) short Asl[4][128][8];
    __shared__ __align__(16) short Wsh[4][128][8];
    __shared__ __align__(16) short Wsl[4][128][8];
    const int tid = threadIdx.x;
    const int bn0 = blockIdx.x * 128, bm0 = blockIdx.y * 128;
    const int wave = tid >> 6, lane = tid & 63;
    const int wr = (wave >> 1) * 64, wc = (wave & 1) * 64;
    const int fr = lane & 15, fg = lane >> 4;
    const int KT = KP >> 5;
    const int srow = tid & 127, skg = tid >> 7;   // lanes contiguous in srow per wave

    const unsigned short* pAh = Ahg + (size_t)(bm0 + srow) * KP + skg * 8;
    const unsigned short* pAl = Alg + (size_t)(bm0 + srow) * KP + skg * 8;
    const unsigned short* pWh = Whg + (size_t)(bn0 + srow) * KP + skg * 8;
    const unsigned short* pWl = Wlg + (size_t)(bn0 + srow) * KP + skg * 8;

    f32x4 acc[4][4];
    #pragma unroll
    for (int i = 0; i < 4; ++i)
        #pragma unroll
        for (int j = 0; j < 4; ++j) acc[i][j] = (f32x4){0.f, 0.f, 0.f, 0.f};

    for (int kt = 0; kt < KT; ++kt) {
        const int koff = kt * 32;
        __syncthreads();   // previous tile consumed by all waves
        gll16(pAh + koff,      &Ash[skg    ][srow][0]);
        gll16(pAh + koff + 16, &Ash[skg + 2][srow][0]);
        gll16(pAl + koff,      &Asl[skg    ][srow][0]);
        gll16(pAl + koff + 16, &Asl[skg + 2][srow][0]);
        gll16(pWh + koff,      &Wsh[skg    ][srow][0]);
        gll16(pWh + koff + 16, &Wsh[skg + 2][srow][0]);
        gll16(pWl + koff,      &Wsl[skg    ][srow][0]);
        gll16(pWl + koff + 16, &Wsl[skg + 2][srow][0]);
        __syncthreads();   // compiler drains vmcnt(0) before s_barrier
        s16x8 ah[4], al[4], wh[4], wl[4];
        #pragma unroll
        for (int i = 0; i < 4; ++i) {
            ah[i] = *(const s16x8*)&Ash[fg][wr + i * 16 + fr][0];
            al[i] = *(const s16x8*)&Asl[fg][wr + i * 16 + fr][0];
            wh[i] = *(const s16x8*)&Wsh[fg][wc + i * 16 + fr][0];
            wl[i] = *(const s16x8*)&Wsl[fg][wc + i * 16 + fr][0];
        }
        #pragma unroll
        for (int i = 0; i < 4; ++i)
            #pragma unroll
            for (int j = 0; j < 4; ++j) {
                acc[i][j] = __builtin_amdgcn_mfma_f32_16x16x32_bf16(ah[i], wh[j], acc[i][j], 0, 0, 0);
                acc[i][j] = __builtin_amdgcn_mfma_f32_16x16x32_bf16(ah[i], wl[j], acc[i][j], 0, 0, 0);
                acc[i][j] = __builtin_amdgcn_mfma_f32_16x16x32_bf16(al[i], wh[j], acc[i][j], 0, 0, 0);
            }
    }
    // C/D layout: col = lane&15, row = (lane>>4)*4 + q
    #pragma unroll
    for (int i = 0; i < 4; ++i) {
        #pragma unroll
        for (int j = 0; j < 4; ++j) {
            int n = bn0 + wc + j * 16 + fr;
            #pragma unroll
            for (int q = 0; q < 4; ++q) {
                int m = bm0 + wr + i * 16 + fg * 4 + q;
                float v = acc[i][j][q];
                if (EPI == 2) v = softplusf(v + bias[n]);
                C[(size_t)m * ldc + n] = v;
            }
        }
    }
}

// ---- fp32 tiled GEMM (x_proj split-K; N=96) ----
__global__ __launch_bounds__(256) void gemm_f32_kernel(
        const float* __restrict__ A, int lda,
        const float* __restrict__ W, int ldw,
        float* __restrict__ C, int ldc,
        int M, int N, int K, int kchunk) {
    __shared__ float As[8][128];
    __shared__ float Bs[8][128];
    if (kchunk) {
        A += (size_t)blockIdx.z * kchunk;
        W += (size_t)blockIdx.z * kchunk;
        C += (size_t)blockIdx.z * M * ldc;
    }
    const int tid = threadIdx.x;
    const int tx = tid & 15, ty = tid >> 4;
    const int bn0 = blockIdx.x * 128, bm0 = blockIdx.y * 128;
    const int lrow = tid >> 1;
    const int lk   = (tid & 1) * 4;
    const int nk = K >> 3;

    float acc[8][8];
    #pragma unroll
    for (int i = 0; i < 8; ++i)
        #pragma unroll
        for (int j = 0; j < 8; ++j) acc[i][j] = 0.f;

    float4 av, wv;
    {
        av = *(const float4*)(A + (size_t)(bm0 + lrow) * lda + lk);
        int n = bn0 + lrow;
        wv = (n < N) ? *(const float4*)(W + (size_t)n * ldw + lk)
                     : make_float4(0.f, 0.f, 0.f, 0.f);
    }
    for (int kt = 0; kt < nk; ++kt) {
        __syncthreads();
        As[lk + 0][lrow] = av.x; As[lk + 1][lrow] = av.y;
        As[lk + 2][lrow] = av.z; As[lk + 3][lrow] = av.w;
        Bs[lk + 0][lrow] = wv.x; Bs[lk + 1][lrow] = wv.y;
        Bs[lk + 2][lrow] = wv.z; Bs[lk + 3][lrow] = wv.w;
        __syncthreads();
        int kt1 = kt + 1;
        if (kt1 < nk) {
            int n = bn0 + lrow;
            av = *(const float4*)(A + (size_t)(bm0 + lrow) * lda + (size_t)kt1 * 8 + lk);
            wv = (n < N) ? *(const float4*)(W + (size_t)n * ldw + (size_t)kt1 * 8 + lk)
                         : make_float4(0.f, 0.f, 0.f, 0.f);
        }
        #pragma unroll
        for (int k = 0; k < 8; ++k) {
            float a[8], b[8];
            #pragma unroll
            for (int i = 0; i < 8; ++i) a[i] = As[k][ty + 16 * i];
            #pragma unroll
            for (int j = 0; j < 8; ++j) b[j] = Bs[k][tx + 16 * j];
            #pragma unroll
            for (int i = 0; i < 8; ++i)
                #pragma unroll
                for (int j = 0; j < 8; ++j)
                    acc[i][j] = fmaf(a[i], b[j], acc[i][j]);
        }
    }
    #pragma unroll
    for (int i = 0; i < 8; ++i) {
        int m = bm0 + ty + 16 * i;
        #pragma unroll
        for (int j = 0; j < 8; ++j) {
            int n = bn0 + tx + 16 * j;
            if (n < N) C[(size_t)m * ldc + n] = acc[i][j];
        }
    }
}

// ---- reduce split-K partials ----
__global__ __launch_bounds__(256) void sk_reduce_kernel(
        const float* __restrict__ part, float* __restrict__ out, int total) {
    int i = blockIdx.x * 256 + threadIdx.x;
    if (i >= total) return;
    float s = 0.f;
    #pragma unroll
    for (int sk = 0; sk < SKX; ++sk) s += part[(size_t)sk * total + i];
    out[i] = s;
}

// ---- depthwise causal conv(4) + bias + SiLU ----
__global__ __launch_bounds__(256) void conv_silu_kernel(
        const float* __restrict__ xz, const float* __restrict__ cw,
        const float* __restrict__ cb, float* __restrict__ u) {
    int idx = blockIdx.x * 256 + threadIdx.x;
    int d  = idx & (D_INNER - 1);
    int bl = idx >> 11;
    int l  = bl & (SEQLEN - 1);
    const float* base = xz + (size_t)bl * 4096 + d;
    float4 w = *(const float4*)(cw + d * 4);
    float s = cb[d];
    if (l >= 3) s = fmaf(base[-3 * 4096], w.x, s);
    if (l >= 2) s = fmaf(base[-2 * 4096], w.y, s);
    if (l >= 1) s = fmaf(base[-1 * 4096], w.z, s);
    s = fmaf(base[0], w.w, s);
    u[idx] = s * __builtin_amdgcn_rcpf(1.f + __expf(-s));
}

// ================= chunk-parallel selective scan (per-thread h[16]) ========
// Thread <-> (b, d); block = 256 consecutive d for one (b, seg).
// grid = NSEG * BATCH * (D_INNER/256) = 32*2*8 = 512 blocks.
__global__ __launch_bounds__(256) void scan_partA(
        const float* __restrict__ delta, const float* __restrict__ u,
        const float* __restrict__ xdbl, const float* __restrict__ A_log,
        float* __restrict__ hF, float* __restrict__ sumd) {
    const int tid = threadIdx.x;
    const int bx  = blockIdx.x;
    const int seg = bx >> 4;
    const int b   = (bx >> 3) & 1;
    const int d   = (bx & 7) * 256 + tid;
    const int t0  = seg * TSEG;
    float An2[16];
    #pragma unroll
    for (int q = 0; q < 4; ++q) {
        float4 a = *(const float4*)(A_log + d * 16 + q * 4);
        An2[q*4+0] = -__expf(a.x) * LOG2E;
        An2[q*4+1] = -__expf(a.y) * LOG2E;
        An2[q*4+2] = -__expf(a.z) * LOG2E;
        An2[q*4+3] = -__expf(a.w) * LOG2E;
    }
    const float* dl = delta + ((size_t)b * SEQLEN + t0) * D_INNER + d;
    const float* uu = u     + ((size_t)b * SEQLEN + t0) * D_INNER + d;
    const float* bc = xdbl  + ((size_t)b * SEQLEN + t0) * 96 + 64;  // block-uniform
    float h[16];
    #pragma unroll
    for (int n = 0; n < 16; ++n) h[n] = 0.f;
    float sd = 0.f;
    float pdv[4], puv[4];
    #pragma unroll
    for (int j = 0; j < 4; ++j) {
        pdv[j] = dl[(size_t)j * D_INNER];
        puv[j] = uu[(size_t)j * D_INNER];
    }
    for (int t4 = 0; t4 < TSEG; t4 += 4) {
        #pragma unroll
        for (int j = 0; j < 4; ++j) {
            const float dv = pdv[j], uv = puv[j];
            if (t4 + 4 < TSEG) {
                pdv[j] = dl[(size_t)(t4 + 4 + j) * D_INNER];
                puv[j] = uu[(size_t)(t4 + 4 + j) * D_INNER];
            }
            const float* bct = bc + (size_t)(t4 + j) * 96;
            float4 B0 = *(const float4*)(bct);
            float4 B1 = *(const float4*)(bct + 4);
            float4 B2 = *(const float4*)(bct + 8);
            float4 B3 = *(const float4*)(bct + 12);
            float Bv[16] = {B0.x,B0.y,B0.z,B0.w, B1.x,B1.y,B1.z,B1.w,
                            B2.x,B2.y,B2.z,B2.w, B3.x,B3.y,B3.z,B3.w};
            const float dvuv = dv * uv;
            sd += dv;
            #pragma unroll
            for (int n = 0; n < 16; ++n)
                h[n] = fmaf(exp2f(dv * An2[n]), h[n], dvuv * Bv[n]);
        }
    }
    const size_t o = (size_t)seg * (BATCH * D_INNER) + (size_t)b * D_INNER + d;
    #pragma unroll
    for (int q = 0; q < 4; ++q)
        *(float4*)(hF + o * 16 + q * 4) =
            make_float4(h[q*4], h[q*4+1], h[q*4+2], h[q*4+3]);
    sumd[o] = sd;
}

// in-place combine: hFin[s] := h_in(s); h advances via stored local scans
__global__ __launch_bounds__(256) void scan_combine(
        const float* __restrict__ A_log, float* __restrict__ hFin,
        const float* __restrict__ sumd) {
    int idx = blockIdx.x * 256 + threadIdx.x;   // row*16 + n, 65536 total
    int n = idx & 15, row = idx >> 4;
    int d = row & (D_INNER - 1);
    float An = -__expf(A_log[d * 16 + n]);
    float f[NSEG], p[NSEG];
    #pragma unroll
    for (int s = 0; s < NSEG; ++s) {
        size_t o = (size_t)s * (BATCH * D_INNER) + row;
        f[s] = hFin[o * 16 + n];
        p[s] = __expf(An * sumd[o]);
    }
    float h = 0.f;
    #pragma unroll
    for (int s = 0; s < NSEG; ++s) {
        size_t o = (size_t)s * (BATCH * D_INNER) + row;
        hFin[o * 16 + n] = h;
        h = fmaf(p[s], h, f[s]);
    }
}

// partB: re-scan from hin, emit y*silu(z). yg aliases delta (same-thread,
// read-before-write per element) -> no __restrict__ on delta/yg.
__global__ __launch_bounds__(256) void scan_partB(
        const float* delta, const float* __restrict__ u,
        const float* __restrict__ xdbl, const float* __restrict__ xz,
        const float* __restrict__ A_log, const float* __restrict__ Dp,
        const float* __restrict__ hin, float* yg) {
    const int tid = threadIdx.x;
    const int bx  = blockIdx.x;
    const int seg = bx >> 4;
    const int b   = (bx >> 3) & 1;
    const int d   = (bx & 7) * 256 + tid;
    const int t0  = seg * TSEG;
    float An2[16];
    #pragma unroll
    for (int q = 0; q < 4; ++q) {
        float4 a = *(const float4*)(A_log + d * 16 + q * 4);
        An2[q*4+0] = -__expf(a.x) * LOG2E;
        An2[q*4+1] = -__expf(a.y) * LOG2E;
        An2[q*4+2] = -__expf(a.z) * LOG2E;
        An2[q*4+3] = -__expf(a.w) * LOG2E;
    }
    const float Dd = Dp[d];
    const float* dl = delta + ((size_t)b * SEQLEN + t0) * D_INNER + d;
    const float* uu = u     + ((size_t)b * SEQLEN + t0) * D_INNER + d;
    const float* bc = xdbl  + ((size_t)b * SEQLEN + t0) * 96 + 64;
    const float* zz = xz    + ((size_t)b * SEQLEN + t0) * 4096 + D_INNER + d;
    float* yo = yg + ((size_t)b * SEQLEN + t0) * D_INNER + d;
    const size_t o = (size_t)seg * (BATCH * D_INNER) + (size_t)b * D_INNER + d;
    float h[16];
    #pragma unroll
    for (int q = 0; q < 4; ++q) {
        float4 hv = *(const float4*)(hin + o * 16 + q * 4);
        h[q*4] = hv.x; h[q*4+1] = hv.y; h[q*4+2] = hv.z; h[q*4+3] = hv.w;
    }
    float pdv[4], puv[4], pzv[4];
    #pragma unroll
    for (int j = 0; j < 4; ++j) {
        pdv[j] = dl[(size_t)j * D_INNER];
        puv[j] = uu[(size_t)j * D_INNER];
        pzv[j] = zz[(size_t)j * 4096];
    }
    for (int t4 = 0; t4 < TSEG; t4 += 4) {
        #pragma unroll
        for (int j = 0; j < 4; ++j) {
            const float dv = pdv[j], uv = puv[j], zv = pzv[j];
            if (t4 + 4 < TSEG) {
                pdv[j] = dl[(size_t)(t4 + 4 + j) * D_INNER];
                puv[j] = uu[(size_t)(t4 + 4 + j) * D_INNER];
                pzv[j] = zz[(size_t)(t4 + 4 + j) * 4096];
            }
            const float* bct = bc + (size_t)(t4 + j) * 96;
            float4 B0 = *(const float4*)(bct);
            float4 B1 = *(const float4*)(bct + 4);
            float4 B2 = *(const float4*)(bct + 8);
            float4 B3 = *(const float4*)(bct + 12);
            float4 C0 = *(const float4*)(bct + 16);
            float4 C1 = *(const float4*)(bct + 20);
            float4 C2 = *(const float4*)(bct + 24);
            float4 C3 = *(const float4*)(bct + 28);
            float Bv[16] = {B0.x,B0.y,B0.z,B0.w, B1.x,B1.y,B1.z,B1.w,
                            B2.x,B2.y,B2.z,B2.w, B3.x,B3.y,B3.z,B3.w};
            float Cv[16] = {C0.x,C0.y,C0.z,C0.w, C1.x,C1.y,C1.z,C1.w,
                            C2.x,C2.y,C2.z,C2.w, C3.x,C3.y,C3.z,C3.w};
            const float dvuv = dv * uv;
            #pragma unroll
            for (int n = 0; n < 16; ++n)
                h[n] = fmaf(exp2f(dv * An2[n]), h[n], dvuv * Bv[n]);
            float acc[4] = {0.f, 0.f, 0.f, 0.f};
            #pragma unroll
            for (int n = 0; n < 16; ++n)
                acc[n & 3] = fmaf(h[n], Cv[n], acc[n & 3]);
            float yv = fmaf(uv, Dd, (acc[0] + acc[1]) + (acc[2] + acc[3]));
            float sig = zv * __builtin_amdgcn_rcpf(1.f + __expf(-zv));
            yo[(size_t)(t4 + j) * D_INNER] = yv * sig;
        }
    }
}

extern "C" void kernel_launch(void* const* d_in, const int* in_sizes, int n_in,
                              void* d_out, int out_size, void* d_ws, size_t ws_size,
                              hipStream_t stream) {
    const float* x        = (const float*)d_in[0];
    const float* w_in     = (const float*)d_in[1];
    const float* lA_in    = (const float*)d_in[2];
    const float* lB_in    = (const float*)d_in[3];
    const float* mask_in  = (const float*)d_in[4];
    const float* conv_w   = (const float*)d_in[5];
    const float* conv_b   = (const float*)d_in[6];
    const float* w_xp     = (const float*)d_in[7];
    const float* w_dt     = (const float*)d_in[8];
    const float* b_dt     = (const float*)d_in[9];
    const float* A_log    = (const float*)d_in[10];
    const float* Dp       = (const float*)d_in[11];
    const float* w_out    = (const float*)d_in[12];
    const float* lA_out   = (const float*)d_in[13];
    const float* lB_out   = (const float*)d_in[14];
    const float* mask_out = (const float*)d_in[15];

    // f32 workspace layout (same footprint as round 3)
    float* ws    = (float*)d_ws;
    float* xz    = ws;                              // [BL,4096]
    float* u     = xz    + (size_t)BL * 4096;       // [BL,2048]
    float* delta = u     + (size_t)BL * D_INNER;    // [BL,2048] (also yg)
    float* xdbl  = delta + (size_t)BL * D_INNER;    // [BL,96]
    float* t16   = xdbl  + (size_t)BL * 96;         // [BL,16]
    float* lbin  = t16   + (size_t)BL * 16;         // [4096,16]
    float* lbout = lbin  + (size_t)4096 * 16;       // [1024,16]

    // bf16 arenas in dead f32 regions
    const size_t AS_IN = (size_t)4096 * 1056, WS_IN = (size_t)4096 * 1056;
    unsigned short* Ahi_in = (unsigned short*)u;
    unsigned short* Alo_in = Ahi_in + AS_IN;
    unsigned short* Whi_in = Alo_in + AS_IN;
    unsigned short* Wlo_in = Whi_in + WS_IN;

    unsigned short* dtb = (unsigned short*)d_out;
    unsigned short* Ahi_dt = dtb;
    unsigned short* Alo_dt = Ahi_dt + (size_t)4096 * 64;
    unsigned short* Whi_dt = Alo_dt + (size_t)4096 * 64;
    unsigned short* Wlo_dt = Whi_dt + (size_t)2048 * 64;

    const size_t AS_OUT = (size_t)4096 * 2080, WS_OUT = (size_t)1024 * 2080;
    unsigned short* Ahi_out = (unsigned short*)xz;
    unsigned short* Alo_out = Ahi_out + AS_OUT;
    unsigned short* Whi_out = Alo_out + AS_OUT;
    unsigned short* Wlo_out = Whi_out + WS_OUT;

    // d_out f32 scratch (pre-final uses)
    float* outf    = (float*)d_out;
    float* xp_part = outf;                                  // [SKX][BL*96] = 12.6MB
    float* hFin    = outf;                                  // [NSEG][4096][16] = 8.39MB
    float* sumd    = hFin + (size_t)NSEG * BATCH * D_INNER * 16;  // +0.52MB

    // 1) LoRA premultiply + t16_in
    premul_kernel<<<(4096 * 16 + 255) / 256, 256, 0, stream>>>(lB_in, mask_in, lbin, 4096 * 16);
    premul_kernel<<<(1024 * 16 + 255) / 256, 256, 0, stream>>>(lB_out, mask_out, lbout, 1024 * 16);
    lora_t_kernel<<<BL, 256, 0, stream>>>(x, D_MODEL, lA_in, D_MODEL, t16);
    // 2) hi/lo conversions for in_proj (K=1024, KP=1056)
    hilo_kernel<<<4096, 256, 0, stream>>>(x,    1024, 256, 1056, Ahi_in, Alo_in, 4096 * 256);
    hilo_kernel<<<4096, 256, 0, stream>>>(w_in, 1024, 256, 1056, Whi_in, Wlo_in, 4096 * 256);
    ext_kernel<<<512, 256, 0, stream>>>(t16,  1024, 1056, Ahi_in, Alo_in, 4096);
    ext_kernel<<<512, 256, 0, stream>>>(lbin, 1024, 1056, Whi_in, Wlo_in, 4096);
    // 3) in_proj MFMA GEMM -> xz
    mfma_gemm<0><<<dim3(32, 32), 256, 0, stream>>>(
        Ahi_in, Alo_in, Whi_in, Wlo_in, 1056, xz, 4096, nullptr);
    // 4) u = silu(conv(xs) + b)
    conv_silu_kernel<<<(BL * D_INNER) / 256, 256, 0, stream>>>(xz, conv_w, conv_b, u);
    // 5) x_proj split-K fp32 -> xdbl
    gemm_f32_kernel<<<dim3(1, BL / 128, SKX), 256, 0, stream>>>(
        u, D_INNER, w_xp, D_INNER, xp_part, 96, BL, 96, KCH, KCH);
    sk_reduce_kernel<<<(BL * 96 + 255) / 256, 256, 0, stream>>>(xp_part, xdbl, BL * 96);
    // 6) dt_proj MFMA (K=64) -> delta = softplus(. + b_dt)
    hilo_kernel<<<(4096 * 16 + 255) / 256, 256, 0, stream>>>(xdbl, 96, 16, 64, Ahi_dt, Alo_dt, 4096 * 16);
    hilo_kernel<<<(2048 * 16 + 255) / 256, 256, 0, stream>>>(w_dt, 64, 16, 64, Whi_dt, Wlo_dt, 2048 * 16);
    mfma_gemm<2><<<dim3(16, 32), 256, 0, stream>>>(
        Ahi_dt, Alo_dt, Whi_dt, Wlo_dt, 64, delta, 2048, b_dt);
    // 7) chunk-parallel selective scan (+ gating); yg aliases delta
    scan_partA<<<NSEG * BATCH * 8, 256, 0, stream>>>(delta, u, xdbl, A_log, hFin, sumd);
    scan_combine<<<(BATCH * D_INNER * 16) / 256, 256, 0, stream>>>(A_log, hFin, sumd);
    scan_partB<<<NSEG * BATCH * 8, 256, 0, stream>>>(delta, u, xdbl, xz, A_log, Dp, hFin, delta);
    // 8) out_proj: t16_out, conversions (K=2048, KP=2080), MFMA -> d_out
    lora_t_kernel<<<BL, 256, 0, stream>>>(delta, D_INNER, lA_out, D_INNER, t16);
    hilo_kernel<<<8192, 256, 0, stream>>>(delta, 2048, 512, 2080, Ahi_out, Alo_out, 4096 * 512);
    hilo_kernel<<<2048, 256, 0, stream>>>(w_out, 2048, 512, 2080, Whi_out, Wlo_out, 1024 * 512);
    ext_kernel<<<512, 256, 0, stream>>>(t16,   2048, 2080, Ahi_out, Alo_out, 4096);
    ext_kernel<<<128, 256, 0, stream>>>(lbout, 2048, 2080, Whi_out, Wlo_out, 1024);
    mfma_gemm<0><<<dim3(8, 32), 256, 0, stream>>>(
        Ahi_out, Alo_out, Whi_out, Wlo_out, 2080, (float*)d_out, 1024, nullptr);
}

// Round 5
// 603.859 us; speedup vs baseline: 3.5219x; 1.0299x over previous
//
#include <hip/hip_runtime.h>
#include <hip/hip_bf16.h>
#include <cstdint>
#include <cstddef>

// Problem constants (from reference)
#define D_MODEL 1024
#define D_INNER 2048
#define NSTATE  16
#define DTRANK  64
#define BATCH   2
#define SEQLEN  2048
#define BL      (BATCH*SEQLEN)   // 4096 tokens
#define NSEG    32
#define TSEG    (SEQLEN/NSEG)    // 64
#define SKX     8                // split-K factor for x_proj
#define KCH     (D_INNER/SKX)    // 256
#define LOG2E   1.4426950408889634f

typedef __attribute__((ext_vector_type(8))) short s16x8;
typedef __attribute__((ext_vector_type(4))) float f32x4;

__device__ __forceinline__ float softplusf(float x) {
    return fmaxf(x, 0.f) + log1pf(expf(-fabsf(x)));
}
__device__ __forceinline__ unsigned short f2bf(float x) {
    __hip_bfloat16 b = __float2bfloat16(x);
    return *(unsigned short*)&b;
}
__device__ __forceinline__ float bf2f(unsigned short u) {
    __hip_bfloat16 b; *(unsigned short*)&b = u;
    return __bfloat162float(b);
}
// async global->LDS, 16B per lane (dest must be linear: base + lane*16)
__device__ __forceinline__ void gll16(const void* g, void* l) {
    __builtin_amdgcn_global_load_lds(
        (const __attribute__((address_space(1))) void*)g,
        (__attribute__((address_space(3))) void*)l, 16, 0, 0);
}

// ---- lbp[n,r] = lora_B[n,r] * mask[n] * 2.0 ----
__global__ __launch_bounds__(256) void premul_kernel(
        const float* __restrict__ lb, const float* __restrict__ mask,
        float* __restrict__ out, int total) {
    int i = blockIdx.x * 256 + threadIdx.x;
    if (i < total) out[i] = lb[i] * mask[i >> 4] * 2.0f;
}

// ---- T[m,r] = sum_k X[m,k] * LA[r,k]   (r < 16) ----
__global__ __launch_bounds__(256) void lora_t_kernel(
        const float* __restrict__ X, int ldx,
        const float* __restrict__ LA, int K,
        float* __restrict__ T) {
    int m = blockIdx.x;
    int r = threadIdx.x >> 4;
    int l = threadIdx.x & 15;
    const float* xrow = X + (size_t)m * ldx;
    const float* arow = LA + (size_t)r * K;
    float s = 0.f;
    for (int k = 4 * l; k < K; k += 64) {
        float4 xv = *(const float4*)(xrow + k);
        float4 av = *(const float4*)(arow + k);
        s += xv.x * av.x + xv.y * av.y + xv.z * av.z + xv.w * av.w;
    }
    #pragma unroll
    for (int o = 8; o; o >>= 1) s += __shfl_xor(s, o, 16);
    if (l == 0) T[(size_t)m * 16 + r] = s;
}

// ---- hi/lo bf16 split: hi=bf16(v), lo=bf16(v-hi) ----
__global__ __launch_bounds__(256) void hilo_kernel(
        const float* __restrict__ src, int lda, int K4, int KP,
        unsigned short* __restrict__ hi, unsigned short* __restrict__ lo,
        int total4) {
    int idx = blockIdx.x * 256 + threadIdx.x;
    if (idx >= total4) return;
    int m = idx / K4;
    int kq = idx - m * K4;
    float4 v = *(const float4*)(src + (size_t)m * lda + kq * 4);
    ushort4 h, l;
    h.x = f2bf(v.x); l.x = f2bf(v.x - bf2f(h.x));
    h.y = f2bf(v.y); l.y = f2bf(v.y - bf2f(h.y));
    h.z = f2bf(v.z); l.z = f2bf(v.z - bf2f(h.z));
    h.w = f2bf(v.w); l.w = f2bf(v.w - bf2f(h.w));
    *(ushort4*)(hi + (size_t)m * KP + kq * 4) = h;
    *(ushort4*)(lo + (size_t)m * KP + kq * 4) = l;
}

// ---- LoRA K-extension columns ----
__global__ __launch_bounds__(256) void ext_kernel(
        const float* __restrict__ t16, int K, int KP,
        unsigned short* __restrict__ hi, unsigned short* __restrict__ lo,
        int M) {
    int idx = blockIdx.x * 256 + threadIdx.x;
    if (idx >= M * 32) return;
    int c = idx & 31, m = idx >> 5;
    unsigned short hv = 0;
    if (c < 16) hv = f2bf(t16[(size_t)m * 16 + c]);
    hi[(size_t)m * KP + K + c] = hv;
    lo[(size_t)m * KP + K + c] = 0;
}

// ---- hi/lo bf16 MFMA GEMM, 2-phase double-buffered prefetch ----
// stage(t+1) issued right after the barrier, overlapping ds_read+MFMA of
// tile t; one barrier per K-tile (drains vmcnt for the prefetched tile).
template<int EPI>
__global__ __launch_bounds__(256, 2) void mfma_gemm(
        const unsigned short* __restrict__ Ahg, const unsigned short* __restrict__ Alg,
        const unsigned short* __restrict__ Whg, const unsigned short* __restrict__ Wlg,
        int KP, float* __restrict__ C, int ldc,
        const float* __restrict__ bias) {
    __shared__ __align__(16) short Ash[2][4][128][8];
    __shared__ __align__(16) short Asl[2][4][128][8];
    __shared__ __align__(16) short Wsh[2][4][128][8];
    __shared__ __align__(16) short Wsl[2][4][128][8];
    const int tid = threadIdx.x;
    // bijective XCD swizzle over the flattened grid (nwg % 8 == 0 for all uses)
    const int nwg = gridDim.x * gridDim.y;
    int bid = blockIdx.y * gridDim.x + blockIdx.x;
    bid = (bid & 7) * (nwg >> 3) + (bid >> 3);
    const int bn0 = (bid % gridDim.x) * 128;
    const int bm0 = (bid / gridDim.x) * 128;
    const int wave = tid >> 6, lane = tid & 63;
    const int wr = (wave >> 1) * 64, wc = (wave & 1) * 64;
    const int fr = lane & 15, fg = lane >> 4;
    const int KT = KP >> 5;
    const int srow = tid & 127, skg = tid >> 7;   // lanes contiguous in srow per wave

    const unsigned short* pAh = Ahg + (size_t)(bm0 + srow) * KP + skg * 8;
    const unsigned short* pAl = Alg + (size_t)(bm0 + srow) * KP + skg * 8;
    const unsigned short* pWh = Whg + (size_t)(bn0 + srow) * KP + skg * 8;
    const unsigned short* pWl = Wlg + (size_t)(bn0 + srow) * KP + skg * 8;

    f32x4 acc[4][4];
    #pragma unroll
    for (int i = 0; i < 4; ++i)
        #pragma unroll
        for (int j = 0; j < 4; ++j) acc[i][j] = (f32x4){0.f, 0.f, 0.f, 0.f};

    auto stage = [&](int kt, int pb) {
        const int koff = kt * 32;
        gll16(pAh + koff,      &Ash[pb][skg    ][srow][0]);
        gll16(pAh + koff + 16, &Ash[pb][skg + 2][srow][0]);
        gll16(pAl + koff,      &Asl[pb][skg    ][srow][0]);
        gll16(pAl + koff + 16, &Asl[pb][skg + 2][srow][0]);
        gll16(pWh + koff,      &Wsh[pb][skg    ][srow][0]);
        gll16(pWh + koff + 16, &Wsh[pb][skg + 2][srow][0]);
        gll16(pWl + koff,      &Wsl[pb][skg    ][srow][0]);
        gll16(pWl + koff + 16, &Wsl[pb][skg + 2][srow][0]);
    };

    stage(0, 0);
    for (int kt = 0; kt < KT; ++kt) {
        const int cur = kt & 1;
        __syncthreads();   // drains vmcnt(0): buf[cur] staged; prev reads done
        if (kt + 1 < KT) stage(kt + 1, cur ^ 1);   // overlaps compute below
        s16x8 ah[4], al[4], wh[4], wl[4];
        #pragma unroll
        for (int i = 0; i < 4; ++i) {
            ah[i] = *(const s16x8*)&Ash[cur][fg][wr + i * 16 + fr][0];
            al[i] = *(const s16x8*)&Asl[cur][fg][wr + i * 16 + fr][0];
            wh[i] = *(const s16x8*)&Wsh[cur][fg][wc + i * 16 + fr][0];
            wl[i] = *(const s16x8*)&Wsl[cur][fg][wc + i * 16 + fr][0];
        }
        #pragma unroll
        for (int i = 0; i < 4; ++i)
            #pragma unroll
            for (int j = 0; j < 4; ++j) {
                acc[i][j] = __builtin_amdgcn_mfma_f32_16x16x32_bf16(ah[i], wh[j], acc[i][j], 0, 0, 0);
                acc[i][j] = __builtin_amdgcn_mfma_f32_16x16x32_bf16(ah[i], wl[j], acc[i][j], 0, 0, 0);
                acc[i][j] = __builtin_amdgcn_mfma_f32_16x16x32_bf16(al[i], wh[j], acc[i][j], 0, 0, 0);
            }
    }
    // C/D layout: col = lane&15, row = (lane>>4)*4 + q
    #pragma unroll
    for (int i = 0; i < 4; ++i) {
        #pragma unroll
        for (int j = 0; j < 4; ++j) {
            int n = bn0 + wc + j * 16 + fr;
            #pragma unroll
            for (int q = 0; q < 4; ++q) {
                int m = bm0 + wr + i * 16 + fg * 4 + q;
                float v = acc[i][j][q];
                if (EPI == 2) v = softplusf(v + bias[n]);
                C[(size_t)m * ldc + n] = v;
            }
        }
    }
}

// ---- fp32 tiled GEMM (x_proj split-K; N=96) ----
__global__ __launch_bounds__(256) void gemm_f32_kernel(
        const float* __restrict__ A, int lda,
        const float* __restrict__ W, int ldw,
        float* __restrict__ C, int ldc,
        int M, int N, int K, int kchunk) {
    __shared__ float As[8][128];
    __shared__ float Bs[8][128];
    if (kchunk) {
        A += (size_t)blockIdx.z * kchunk;
        W += (size_t)blockIdx.z * kchunk;
        C += (size_t)blockIdx.z * M * ldc;
    }
    const int tid = threadIdx.x;
    const int tx = tid & 15, ty = tid >> 4;
    const int bn0 = blockIdx.x * 128, bm0 = blockIdx.y * 128;
    const int lrow = tid >> 1;
    const int lk   = (tid & 1) * 4;
    const int nk = K >> 3;

    float acc[8][8];
    #pragma unroll
    for (int i = 0; i < 8; ++i)
        #pragma unroll
        for (int j = 0; j < 8; ++j) acc[i][j] = 0.f;

    float4 av, wv;
    {
        av = *(const float4*)(A + (size_t)(bm0 + lrow) * lda + lk);
        int n = bn0 + lrow;
        wv = (n < N) ? *(const float4*)(W + (size_t)n * ldw + lk)
                     : make_float4(0.f, 0.f, 0.f, 0.f);
    }
    for (int kt = 0; kt < nk; ++kt) {
        __syncthreads();
        As[lk + 0][lrow] = av.x; As[lk + 1][lrow] = av.y;
        As[lk + 2][lrow] = av.z; As[lk + 3][lrow] = av.w;
        Bs[lk + 0][lrow] = wv.x; Bs[lk + 1][lrow] = wv.y;
        Bs[lk + 2][lrow] = wv.z; Bs[lk + 3][lrow] = wv.w;
        __syncthreads();
        int kt1 = kt + 1;
        if (kt1 < nk) {
            int n = bn0 + lrow;
            av = *(const float4*)(A + (size_t)(bm0 + lrow) * lda + (size_t)kt1 * 8 + lk);
            wv = (n < N) ? *(const float4*)(W + (size_t)n * ldw + (size_t)kt1 * 8 + lk)
                         : make_float4(0.f, 0.f, 0.f, 0.f);
        }
        #pragma unroll
        for (int k = 0; k < 8; ++k) {
            float a[8], b[8];
            #pragma unroll
            for (int i = 0; i < 8; ++i) a[i] = As[k][ty + 16 * i];
            #pragma unroll
            for (int j = 0; j < 8; ++j) b[j] = Bs[k][tx + 16 * j];
            #pragma unroll
            for (int i = 0; i < 8; ++i)
                #pragma unroll
                for (int j = 0; j < 8; ++j)
                    acc[i][j] = fmaf(a[i], b[j], acc[i][j]);
        }
    }
    #pragma unroll
    for (int i = 0; i < 8; ++i) {
        int m = bm0 + ty + 16 * i;
        #pragma unroll
        for (int j = 0; j < 8; ++j) {
            int n = bn0 + tx + 16 * j;
            if (n < N) C[(size_t)m * ldc + n] = acc[i][j];
        }
    }
}

// ---- reduce split-K partials ----
__global__ __launch_bounds__(256) void sk_reduce_kernel(
        const float* __restrict__ part, float* __restrict__ out, int total) {
    int i = blockIdx.x * 256 + threadIdx.x;
    if (i >= total) return;
    float s = 0.f;
    #pragma unroll
    for (int sk = 0; sk < SKX; ++sk) s += part[(size_t)sk * total + i];
    out[i] = s;
}

// ---- depthwise causal conv(4) + bias + SiLU ----
__global__ __launch_bounds__(256) void conv_silu_kernel(
        const float* __restrict__ xz, const float* __restrict__ cw,
        const float* __restrict__ cb, float* __restrict__ u) {
    int idx = blockIdx.x * 256 + threadIdx.x;
    int d  = idx & (D_INNER - 1);
    int bl = idx >> 11;
    int l  = bl & (SEQLEN - 1);
    const float* base = xz + (size_t)bl * 4096 + d;
    float4 w = *(const float4*)(cw + d * 4);
    float s = cb[d];
    if (l >= 3) s = fmaf(base[-3 * 4096], w.x, s);
    if (l >= 2) s = fmaf(base[-2 * 4096], w.y, s);
    if (l >= 1) s = fmaf(base[-1 * 4096], w.z, s);
    s = fmaf(base[0], w.w, s);
    u[idx] = s * __builtin_amdgcn_rcpf(1.f + __expf(-s));
}

// ================= chunk-parallel selective scan (per-thread h[16]) ========
__global__ __launch_bounds__(256) void scan_partA(
        const float* __restrict__ delta, const float* __restrict__ u,
        const float* __restrict__ xdbl, const float* __restrict__ A_log,
        float* __restrict__ hF, float* __restrict__ sumd) {
    const int tid = threadIdx.x;
    const int bx  = blockIdx.x;
    const int seg = bx >> 4;
    const int b   = (bx >> 3) & 1;
    const int d   = (bx & 7) * 256 + tid;
    const int t0  = seg * TSEG;
    float An2[16];
    #pragma unroll
    for (int q = 0; q < 4; ++q) {
        float4 a = *(const float4*)(A_log + d * 16 + q * 4);
        An2[q*4+0] = -__expf(a.x) * LOG2E;
        An2[q*4+1] = -__expf(a.y) * LOG2E;
        An2[q*4+2] = -__expf(a.z) * LOG2E;
        An2[q*4+3] = -__expf(a.w) * LOG2E;
    }
    const float* dl = delta + ((size_t)b * SEQLEN + t0) * D_INNER + d;
    const float* uu = u     + ((size_t)b * SEQLEN + t0) * D_INNER + d;
    const float* bc = xdbl  + ((size_t)b * SEQLEN + t0) * 96 + 64;
    float h[16];
    #pragma unroll
    for (int n = 0; n < 16; ++n) h[n] = 0.f;
    float sd = 0.f;
    float pdv[4], puv[4];
    #pragma unroll
    for (int j = 0; j < 4; ++j) {
        pdv[j] = dl[(size_t)j * D_INNER];
        puv[j] = uu[(size_t)j * D_INNER];
    }
    for (int t4 = 0; t4 < TSEG; t4 += 4) {
        #pragma unroll
        for (int j = 0; j < 4; ++j) {
            const float dv = pdv[j], uv = puv[j];
            if (t4 + 4 < TSEG) {
                pdv[j] = dl[(size_t)(t4 + 4 + j) * D_INNER];
                puv[j] = uu[(size_t)(t4 + 4 + j) * D_INNER];
            }
            const float* bct = bc + (size_t)(t4 + j) * 96;
            float4 B0 = *(const float4*)(bct);
            float4 B1 = *(const float4*)(bct + 4);
            float4 B2 = *(const float4*)(bct + 8);
            float4 B3 = *(const float4*)(bct + 12);
            float Bv[16] = {B0.x,B0.y,B0.z,B0.w, B1.x,B1.y,B1.z,B1.w,
                            B2.x,B2.y,B2.z,B2.w, B3.x,B3.y,B3.z,B3.w};
            const float dvuv = dv * uv;
            sd += dv;
            #pragma unroll
            for (int n = 0; n < 16; ++n)
                h[n] = fmaf(exp2f(dv * An2[n]), h[n], dvuv * Bv[n]);
        }
    }
    const size_t o = (size_t)seg * (BATCH * D_INNER) + (size_t)b * D_INNER + d;
    #pragma unroll
    for (int q = 0; q < 4; ++q)
        *(float4*)(hF + o * 16 + q * 4) =
            make_float4(h[q*4], h[q*4+1], h[q*4+2], h[q*4+3]);
    sumd[o] = sd;
}

__global__ __launch_bounds__(256) void scan_combine(
        const float* __restrict__ A_log, float* __restrict__ hFin,
        const float* __restrict__ sumd) {
    int idx = blockIdx.x * 256 + threadIdx.x;
    int n = idx & 15, row = idx >> 4;
    int d = row & (D_INNER - 1);
    float An = -__expf(A_log[d * 16 + n]);
    float f[NSEG], p[NSEG];
    #pragma unroll
    for (int s = 0; s < NSEG; ++s) {
        size_t o = (size_t)s * (BATCH * D_INNER) + row;
        f[s] = hFin[o * 16 + n];
        p[s] = __expf(An * sumd[o]);
    }
    float h = 0.f;
    #pragma unroll
    for (int s = 0; s < NSEG; ++s) {
        size_t o = (size_t)s * (BATCH * D_INNER) + row;
        hFin[o * 16 + n] = h;
        h = fmaf(p[s], h, f[s]);
    }
}

__global__ __launch_bounds__(256) void scan_partB(
        const float* delta, const float* __restrict__ u,
        const float* __restrict__ xdbl, const float* __restrict__ xz,
        const float* __restrict__ A_log, const float* __restrict__ Dp,
        const float* __restrict__ hin, float* yg) {
    const int tid = threadIdx.x;
    const int bx  = blockIdx.x;
    const int seg = bx >> 4;
    const int b   = (bx >> 3) & 1;
    const int d   = (bx & 7) * 256 + tid;
    const int t0  = seg * TSEG;
    float An2[16];
    #pragma unroll
    for (int q = 0; q < 4; ++q) {
        float4 a = *(const float4*)(A_log + d * 16 + q * 4);
        An2[q*4+0] = -__expf(a.x) * LOG2E;
        An2[q*4+1] = -__expf(a.y) * LOG2E;
        An2[q*4+2] = -__expf(a.z) * LOG2E;
        An2[q*4+3] = -__expf(a.w) * LOG2E;
    }
    const float Dd = Dp[d];
    const float* dl = delta + ((size_t)b * SEQLEN + t0) * D_INNER + d;
    const float* uu = u     + ((size_t)b * SEQLEN + t0) * D_INNER + d;
    const float* bc = xdbl  + ((size_t)b * SEQLEN + t0) * 96 + 64;
    const float* zz = xz    + ((size_t)b * SEQLEN + t0) * 4096 + D_INNER + d;
    float* yo = yg + ((size_t)b * SEQLEN + t0) * D_INNER + d;
    const size_t o = (size_t)seg * (BATCH * D_INNER) + (size_t)b * D_INNER + d;
    float h[16];
    #pragma unroll
    for (int q = 0; q < 4; ++q) {
        float4 hv = *(const float4*)(hin + o * 16 + q * 4);
        h[q*4] = hv.x; h[q*4+1] = hv.y; h[q*4+2] = hv.z; h[q*4+3] = hv.w;
    }
    float pdv[4], puv[4], pzv[4];
    #pragma unroll
    for (int j = 0; j < 4; ++j) {
        pdv[j] = dl[(size_t)j * D_INNER];
        puv[j] = uu[(size_t)j * D_INNER];
        pzv[j] = zz[(size_t)j * 4096];
    }
    for (int t4 = 0; t4 < TSEG; t4 += 4) {
        #pragma unroll
        for (int j = 0; j < 4; ++j) {
            const float dv = pdv[j], uv = puv[j], zv = pzv[j];
            if (t4 + 4 < TSEG) {
                pdv[j] = dl[(size_t)(t4 + 4 + j) * D_INNER];
                puv[j] = uu[(size_t)(t4 + 4 + j) * D_INNER];
                pzv[j] = zz[(size_t)(t4 + 4 + j) * 4096];
            }
            const float* bct = bc + (size_t)(t4 + j) * 96;
            float4 B0 = *(const float4*)(bct);
            float4 B1 = *(const float4*)(bct + 4);
            float4 B2 = *(const float4*)(bct + 8);
            float4 B3 = *(const float4*)(bct + 12);
            float4 C0 = *(const float4*)(bct + 16);
            float4 C1 = *(const float4*)(bct + 20);
            float4 C2 = *(const float4*)(bct + 24);
            float4 C3 = *(const float4*)(bct + 28);
            float Bv[16] = {B0.x,B0.y,B0.z,B0.w, B1.x,B1.y,B1.z,B1.w,
                            B2.x,B2.y,B2.z,B2.w, B3.x,B3.y,B3.z,B3.w};
            float Cv[16] = {C0.x,C0.y,C0.z,C0.w, C1.x,C1.y,C1.z,C1.w,
                            C2.x,C2.y,C2.z,C2.w, C3.x,C3.y,C3.z,C3.w};
            const float dvuv = dv * uv;
            #pragma unroll
            for (int n = 0; n < 16; ++n)
                h[n] = fmaf(exp2f(dv * An2[n]), h[n], dvuv * Bv[n]);
            float acc[4] = {0.f, 0.f, 0.f, 0.f};
            #pragma unroll
            for (int n = 0; n < 16; ++n)
                acc[n & 3] = fmaf(h[n], Cv[n], acc[n & 3]);
            float yv = fmaf(uv, Dd, (acc[0] + acc[1]) + (acc[2] + acc[3]));
            float sig = zv * __builtin_amdgcn_rcpf(1.f + __expf(-zv));
            yo[(size_t)(t4 + j) * D_INNER] = yv * sig;
        }
    }
}

extern "C" void kernel_launch(void* const* d_in, const int* in_sizes, int n_in,
                              void* d_out, int out_size, void* d_ws, size_t ws_size,
                              hipStream_t stream) {
    const float* x        = (const float*)d_in[0];
    const float* w_in     = (const float*)d_in[1];
    const float* lA_in    = (const float*)d_in[2];
    const float* lB_in    = (const float*)d_in[3];
    const float* mask_in  = (const float*)d_in[4];
    const float* conv_w   = (const float*)d_in[5];
    const float* conv_b   = (const float*)d_in[6];
    const float* w_xp     = (const float*)d_in[7];
    const float* w_dt     = (const float*)d_in[8];
    const float* b_dt     = (const float*)d_in[9];
    const float* A_log    = (const float*)d_in[10];
    const float* Dp       = (const float*)d_in[11];
    const float* w_out    = (const float*)d_in[12];
    const float* lA_out   = (const float*)d_in[13];
    const float* lB_out   = (const float*)d_in[14];
    const float* mask_out = (const float*)d_in[15];

    // f32 workspace layout
    float* ws    = (float*)d_ws;
    float* xz    = ws;                              // [BL,4096]
    float* u     = xz    + (size_t)BL * 4096;       // [BL,2048]
    float* delta = u     + (size_t)BL * D_INNER;    // [BL,2048] (also yg)
    float* xdbl  = delta + (size_t)BL * D_INNER;    // [BL,96]
    float* t16   = xdbl  + (size_t)BL * 96;         // [BL,16]
    float* lbin  = t16   + (size_t)BL * 16;         // [4096,16]
    float* lbout = lbin  + (size_t)4096 * 16;       // [1024,16]

    // bf16 arenas in dead f32 regions
    const size_t AS_IN = (size_t)4096 * 1056, WS_IN = (size_t)4096 * 1056;
    unsigned short* Ahi_in = (unsigned short*)u;
    unsigned short* Alo_in = Ahi_in + AS_IN;
    unsigned short* Whi_in = Alo_in + AS_IN;
    unsigned short* Wlo_in = Whi_in + WS_IN;

    unsigned short* dtb = (unsigned short*)d_out;
    unsigned short* Ahi_dt = dtb;
    unsigned short* Alo_dt = Ahi_dt + (size_t)4096 * 64;
    unsigned short* Whi_dt = Alo_dt + (size_t)4096 * 64;
    unsigned short* Wlo_dt = Whi_dt + (size_t)2048 * 64;

    const size_t AS_OUT = (size_t)4096 * 2080, WS_OUT = (size_t)1024 * 2080;
    unsigned short* Ahi_out = (unsigned short*)xz;
    unsigned short* Alo_out = Ahi_out + AS_OUT;
    unsigned short* Whi_out = Alo_out + AS_OUT;
    unsigned short* Wlo_out = Whi_out + WS_OUT;

    // d_out f32 scratch (pre-final uses)
    float* outf    = (float*)d_out;
    float* xp_part = outf;                                  // [SKX][BL*96]
    float* hFin    = outf;                                  // [NSEG][4096][16]
    float* sumd    = hFin + (size_t)NSEG * BATCH * D_INNER * 16;

    // 1) LoRA premultiply + t16_in
    premul_kernel<<<(4096 * 16 + 255) / 256, 256, 0, stream>>>(lB_in, mask_in, lbin, 4096 * 16);
    premul_kernel<<<(1024 * 16 + 255) / 256, 256, 0, stream>>>(lB_out, mask_out, lbout, 1024 * 16);
    lora_t_kernel<<<BL, 256, 0, stream>>>(x, D_MODEL, lA_in, D_MODEL, t16);
    // 2) hi/lo conversions for in_proj (K=1024, KP=1056)
    hilo_kernel<<<4096, 256, 0, stream>>>(x,    1024, 256, 1056, Ahi_in, Alo_in, 4096 * 256);
    hilo_kernel<<<4096, 256, 0, stream>>>(w_in, 1024, 256, 1056, Whi_in, Wlo_in, 4096 * 256);
    ext_kernel<<<512, 256, 0, stream>>>(t16,  1024, 1056, Ahi_in, Alo_in, 4096);
    ext_kernel<<<512, 256, 0, stream>>>(lbin, 1024, 1056, Whi_in, Wlo_in, 4096);
    // 3) in_proj MFMA GEMM -> xz
    mfma_gemm<0><<<dim3(32, 32), 256, 0, stream>>>(
        Ahi_in, Alo_in, Whi_in, Wlo_in, 1056, xz, 4096, nullptr);
    // 4) u = silu(conv(xs) + b)
    conv_silu_kernel<<<(BL * D_INNER) / 256, 256, 0, stream>>>(xz, conv_w, conv_b, u);
    // 5) x_proj split-K fp32 -> xdbl
    gemm_f32_kernel<<<dim3(1, BL / 128, SKX), 256, 0, stream>>>(
        u, D_INNER, w_xp, D_INNER, xp_part, 96, BL, 96, KCH, KCH);
    sk_reduce_kernel<<<(BL * 96 + 255) / 256, 256, 0, stream>>>(xp_part, xdbl, BL * 96);
    // 6) dt_proj MFMA (K=64) -> delta = softplus(. + b_dt)
    hilo_kernel<<<(4096 * 16 + 255) / 256, 256, 0, stream>>>(xdbl, 96, 16, 64, Ahi_dt, Alo_dt, 4096 * 16);
    hilo_kernel<<<(2048 * 16 + 255) / 256, 256, 0, stream>>>(w_dt, 64, 16, 64, Whi_dt, Wlo_dt, 2048 * 16);
    mfma_gemm<2><<<dim3(16, 32), 256, 0, stream>>>(
        Ahi_dt, Alo_dt, Whi_dt, Wlo_dt, 64, delta, 2048, b_dt);
    // 7) chunk-parallel selective scan (+ gating); yg aliases delta
    scan_partA<<<NSEG * BATCH * 8, 256, 0, stream>>>(delta, u, xdbl, A_log, hFin, sumd);
    scan_combine<<<(BATCH * D_INNER * 16) / 256, 256, 0, stream>>>(A_log, hFin, sumd);
    scan_partB<<<NSEG * BATCH * 8, 256, 0, stream>>>(delta, u, xdbl, xz, A_log, Dp, hFin, delta);
    // 8) out_proj: t16_out, conversions (K=2048, KP=2080), MFMA -> d_out
    lora_t_kernel<<<BL, 256, 0, stream>>>(delta, D_INNER, lA_out, D_INNER, t16);
    hilo_kernel<<<8192, 256, 0, stream>>>(delta, 2048, 512, 2080, Ahi_out, Alo_out, 4096 * 512);
    hilo_kernel<<<2048, 256, 0, stream>>>(w_out, 2048, 512, 2080, Whi_out, Wlo_out, 1024 * 512);
    ext_kernel<<<512, 256, 0, stream>>>(t16,   2048, 2080, Ahi_out, Alo_out, 4096);
    ext_kernel<<<128, 256, 0, stream>>>(lbout, 2048, 2080, Whi_out, Wlo_out, 1024);
    mfma_gemm<0><<<dim3(8, 32), 256, 0, stream>>>(
        Ahi_out, Alo_out, Whi_out, Wlo_out, 2080, (float*)d_out, 1024, nullptr);
}

// Round 6
// 596.826 us; speedup vs baseline: 3.5634x; 1.0118x over previous
//
#include <hip/hip_runtime.h>
#include <hip/hip_bf16.h>
#include <cstdint>
#include <cstddef>

// Problem constants (from reference)
#define D_MODEL 1024
#define D_INNER 2048
#define NSTATE  16
#define DTRANK  64
#define BATCH   2
#define SEQLEN  2048
#define BL      (BATCH*SEQLEN)   // 4096 tokens
#define NSEG    32
#define TSEG    (SEQLEN/NSEG)    // 64
#define SKX     8                // split-K factor for x_proj
#define KCH     (D_INNER/SKX)    // 256
#define LOG2E   1.4426950408889634f

typedef __attribute__((ext_vector_type(8))) short s16x8;
typedef __attribute__((ext_vector_type(4))) float f32x4;

__device__ __forceinline__ float softplusf(float x) {
    return fmaxf(x, 0.f) + log1pf(expf(-fabsf(x)));
}
__device__ __forceinline__ unsigned short f2bf(float x) {
    __hip_bfloat16 b = __float2bfloat16(x);
    return *(unsigned short*)&b;
}
__device__ __forceinline__ float bf2f(unsigned short u) {
    __hip_bfloat16 b; *(unsigned short*)&b = u;
    return __bfloat162float(b);
}
// async global->LDS, 16B per lane (dest must be linear: base + lane*16)
__device__ __forceinline__ void gll16(const void* g, void* l) {
    __builtin_amdgcn_global_load_lds(
        (const __attribute__((address_space(1))) void*)g,
        (__attribute__((address_space(3))) void*)l, 16, 0, 0);
}

// ---- lbp[n,r] = lora_B[n,r] * mask[n] * 2.0 ----
__global__ __launch_bounds__(256) void premul_kernel(
        const float* __restrict__ lb, const float* __restrict__ mask,
        float* __restrict__ out, int total) {
    int i = blockIdx.x * 256 + threadIdx.x;
    if (i < total) out[i] = lb[i] * mask[i >> 4] * 2.0f;
}

// ---- T[m,r] = sum_k X[m,k] * LA[r,k]   (r < 16) ----
__global__ __launch_bounds__(256) void lora_t_kernel(
        const float* __restrict__ X, int ldx,
        const float* __restrict__ LA, int K,
        float* __restrict__ T) {
    int m = blockIdx.x;
    int r = threadIdx.x >> 4;
    int l = threadIdx.x & 15;
    const float* xrow = X + (size_t)m * ldx;
    const float* arow = LA + (size_t)r * K;
    float s = 0.f;
    for (int k = 4 * l; k < K; k += 64) {
        float4 xv = *(const float4*)(xrow + k);
        float4 av = *(const float4*)(arow + k);
        s += xv.x * av.x + xv.y * av.y + xv.z * av.z + xv.w * av.w;
    }
    #pragma unroll
    for (int o = 8; o; o >>= 1) s += __shfl_xor(s, o, 16);
    if (l == 0) T[(size_t)m * 16 + r] = s;
}

// ---- hi/lo bf16 split: hi=bf16(v), lo=bf16(v-hi) ----
__global__ __launch_bounds__(256) void hilo_kernel(
        const float* __restrict__ src, int lda, int K4, int KP,
        unsigned short* __restrict__ hi, unsigned short* __restrict__ lo,
        int total4) {
    int idx = blockIdx.x * 256 + threadIdx.x;
    if (idx >= total4) return;
    int m = idx / K4;
    int kq = idx - m * K4;
    float4 v = *(const float4*)(src + (size_t)m * lda + kq * 4);
    ushort4 h, l;
    h.x = f2bf(v.x); l.x = f2bf(v.x - bf2f(h.x));
    h.y = f2bf(v.y); l.y = f2bf(v.y - bf2f(h.y));
    h.z = f2bf(v.z); l.z = f2bf(v.z - bf2f(h.z));
    h.w = f2bf(v.w); l.w = f2bf(v.w - bf2f(h.w));
    *(ushort4*)(hi + (size_t)m * KP + kq * 4) = h;
    *(ushort4*)(lo + (size_t)m * KP + kq * 4) = l;
}

// ---- LoRA K-extension columns ----
__global__ __launch_bounds__(256) void ext_kernel(
        const float* __restrict__ t16, int K, int KP,
        unsigned short* __restrict__ hi, unsigned short* __restrict__ lo,
        int M) {
    int idx = blockIdx.x * 256 + threadIdx.x;
    if (idx >= M * 32) return;
    int c = idx & 31, m = idx >> 5;
    unsigned short hv = 0;
    if (c < 16) hv = f2bf(t16[(size_t)m * 16 + c]);
    hi[(size_t)m * KP + K + c] = hv;
    lo[(size_t)m * KP + K + c] = 0;
}

// ---- hi/lo bf16 MFMA GEMM, counted-vmcnt 2-deep pipeline (T3+T4) ----
// Per tile: vmcnt(8) [tile kt landed, kt+1 in flight] -> barrier ->
// ds_read -> lgkmcnt(0) -> barrier -> refill buf[cur] with tile kt+2 ->
// 48 MFMA. Each stage gets ~2 compute phases of latency cover; vmcnt
// never drains to 0 in the main loop.
template<int EPI>
__global__ __launch_bounds__(256, 2) void mfma_gemm(
        const unsigned short* __restrict__ Ahg, const unsigned short* __restrict__ Alg,
        const unsigned short* __restrict__ Whg, const unsigned short* __restrict__ Wlg,
        int KP, float* __restrict__ C, int ldc,
        const float* __restrict__ bias) {
    __shared__ __align__(16) short Ash[2][4][128][8];
    __shared__ __align__(16) short Asl[2][4][128][8];
    __shared__ __align__(16) short Wsh[2][4][128][8];
    __shared__ __align__(16) short Wsl[2][4][128][8];
    const int tid = threadIdx.x;
    const int bn0 = blockIdx.x * 128, bm0 = blockIdx.y * 128;  // natural mapping
    const int wave = tid >> 6, lane = tid & 63;
    const int wr = (wave >> 1) * 64, wc = (wave & 1) * 64;
    const int fr = lane & 15, fg = lane >> 4;
    const int KT = KP >> 5;
    const int srow = tid & 127, skg = tid >> 7;   // lanes contiguous in srow per wave

    const unsigned short* pAh = Ahg + (size_t)(bm0 + srow) * KP + skg * 8;
    const unsigned short* pAl = Alg + (size_t)(bm0 + srow) * KP + skg * 8;
    const unsigned short* pWh = Whg + (size_t)(bn0 + srow) * KP + skg * 8;
    const unsigned short* pWl = Wlg + (size_t)(bn0 + srow) * KP + skg * 8;

    f32x4 acc[4][4];
    #pragma unroll
    for (int i = 0; i < 4; ++i)
        #pragma unroll
        for (int j = 0; j < 4; ++j) acc[i][j] = (f32x4){0.f, 0.f, 0.f, 0.f};

    auto stage = [&](int kt, int pb) {
        const int koff = kt * 32;
        gll16(pAh + koff,      &Ash[pb][skg    ][srow][0]);
        gll16(pAh + koff + 16, &Ash[pb][skg + 2][srow][0]);
        gll16(pAl + koff,      &Asl[pb][skg    ][srow][0]);
        gll16(pAl + koff + 16, &Asl[pb][skg + 2][srow][0]);
        gll16(pWh + koff,      &Wsh[pb][skg    ][srow][0]);
        gll16(pWh + koff + 16, &Wsh[pb][skg + 2][srow][0]);
        gll16(pWl + koff,      &Wsl[pb][skg    ][srow][0]);
        gll16(pWl + koff + 16, &Wsl[pb][skg + 2][srow][0]);
    };

    stage(0, 0);
    if (KT > 1) stage(1, 1);
    for (int kt = 0; kt < KT; ++kt) {
        const int cur = kt & 1;
        if (kt + 1 < KT) {
            asm volatile("s_waitcnt vmcnt(8)" ::: "memory");   // tile kt landed
        } else {
            asm volatile("s_waitcnt vmcnt(0)" ::: "memory");
        }
        __builtin_amdgcn_sched_barrier(0);
        __builtin_amdgcn_s_barrier();           // all waves: buf[cur] full
        __builtin_amdgcn_sched_barrier(0);
        s16x8 ah[4], al[4], wh[4], wl[4];
        #pragma unroll
        for (int i = 0; i < 4; ++i) {
            ah[i] = *(const s16x8*)&Ash[cur][fg][wr + i * 16 + fr][0];
            al[i] = *(const s16x8*)&Asl[cur][fg][wr + i * 16 + fr][0];
            wh[i] = *(const s16x8*)&Wsh[cur][fg][wc + i * 16 + fr][0];
            wl[i] = *(const s16x8*)&Wsl[cur][fg][wc + i * 16 + fr][0];
        }
        asm volatile("s_waitcnt lgkmcnt(0)" ::: "memory");     // reads done
        __builtin_amdgcn_sched_barrier(0);
        __builtin_amdgcn_s_barrier();           // all waves done reading buf[cur]
        __builtin_amdgcn_sched_barrier(0);
        if (kt + 2 < KT) stage(kt + 2, cur);    // refill; lands 2 iters later
        __builtin_amdgcn_sched_barrier(0);
        #pragma unroll
        for (int i = 0; i < 4; ++i)
            #pragma unroll
            for (int j = 0; j < 4; ++j) {
                acc[i][j] = __builtin_amdgcn_mfma_f32_16x16x32_bf16(ah[i], wh[j], acc[i][j], 0, 0, 0);
                acc[i][j] = __builtin_amdgcn_mfma_f32_16x16x32_bf16(ah[i], wl[j], acc[i][j], 0, 0, 0);
                acc[i][j] = __builtin_amdgcn_mfma_f32_16x16x32_bf16(al[i], wh[j], acc[i][j], 0, 0, 0);
            }
    }
    // C/D layout: col = lane&15, row = (lane>>4)*4 + q
    #pragma unroll
    for (int i = 0; i < 4; ++i) {
        #pragma unroll
        for (int j = 0; j < 4; ++j) {
            int n = bn0 + wc + j * 16 + fr;
            #pragma unroll
            for (int q = 0; q < 4; ++q) {
                int m = bm0 + wr + i * 16 + fg * 4 + q;
                float v = acc[i][j][q];
                if (EPI == 2) v = softplusf(v + bias[n]);
                C[(size_t)m * ldc + n] = v;
            }
        }
    }
}

// ---- fp32 tiled GEMM (x_proj split-K; N=96) ----
__global__ __launch_bounds__(256) void gemm_f32_kernel(
        const float* __restrict__ A, int lda,
        const float* __restrict__ W, int ldw,
        float* __restrict__ C, int ldc,
        int M, int N, int K, int kchunk) {
    __shared__ float As[8][128];
    __shared__ float Bs[8][128];
    if (kchunk) {
        A += (size_t)blockIdx.z * kchunk;
        W += (size_t)blockIdx.z * kchunk;
        C += (size_t)blockIdx.z * M * ldc;
    }
    const int tid = threadIdx.x;
    const int tx = tid & 15, ty = tid >> 4;
    const int bn0 = blockIdx.x * 128, bm0 = blockIdx.y * 128;
    const int lrow = tid >> 1;
    const int lk   = (tid & 1) * 4;
    const int nk = K >> 3;

    float acc[8][8];
    #pragma unroll
    for (int i = 0; i < 8; ++i)
        #pragma unroll
        for (int j = 0; j < 8; ++j) acc[i][j] = 0.f;

    float4 av, wv;
    {
        av = *(const float4*)(A + (size_t)(bm0 + lrow) * lda + lk);
        int n = bn0 + lrow;
        wv = (n < N) ? *(const float4*)(W + (size_t)n * ldw + lk)
                     : make_float4(0.f, 0.f, 0.f, 0.f);
    }
    for (int kt = 0; kt < nk; ++kt) {
        __syncthreads();
        As[lk + 0][lrow] = av.x; As[lk + 1][lrow] = av.y;
        As[lk + 2][lrow] = av.z; As[lk + 3][lrow] = av.w;
        Bs[lk + 0][lrow] = wv.x; Bs[lk + 1][lrow] = wv.y;
        Bs[lk + 2][lrow] = wv.z; Bs[lk + 3][lrow] = wv.w;
        __syncthreads();
        int kt1 = kt + 1;
        if (kt1 < nk) {
            int n = bn0 + lrow;
            av = *(const float4*)(A + (size_t)(bm0 + lrow) * lda + (size_t)kt1 * 8 + lk);
            wv = (n < N) ? *(const float4*)(W + (size_t)n * ldw + (size_t)kt1 * 8 + lk)
                         : make_float4(0.f, 0.f, 0.f, 0.f);
        }
        #pragma unroll
        for (int k = 0; k < 8; ++k) {
            float a[8], b[8];
            #pragma unroll
            for (int i = 0; i < 8; ++i) a[i] = As[k][ty + 16 * i];
            #pragma unroll
            for (int j = 0; j < 8; ++j) b[j] = Bs[k][tx + 16 * j];
            #pragma unroll
            for (int i = 0; i < 8; ++i)
                #pragma unroll
                for (int j = 0; j < 8; ++j)
                    acc[i][j] = fmaf(a[i], b[j], acc[i][j]);
        }
    }
    #pragma unroll
    for (int i = 0; i < 8; ++i) {
        int m = bm0 + ty + 16 * i;
        #pragma unroll
        for (int j = 0; j < 8; ++j) {
            int n = bn0 + tx + 16 * j;
            if (n < N) C[(size_t)m * ldc + n] = acc[i][j];
        }
    }
}

// ---- reduce split-K partials ----
__global__ __launch_bounds__(256) void sk_reduce_kernel(
        const float* __restrict__ part, float* __restrict__ out, int total) {
    int i = blockIdx.x * 256 + threadIdx.x;
    if (i >= total) return;
    float s = 0.f;
    #pragma unroll
    for (int sk = 0; sk < SKX; ++sk) s += part[(size_t)sk * total + i];
    out[i] = s;
}

// ---- depthwise causal conv(4) + bias + SiLU ----
__global__ __launch_bounds__(256) void conv_silu_kernel(
        const float* __restrict__ xz, const float* __restrict__ cw,
        const float* __restrict__ cb, float* __restrict__ u) {
    int idx = blockIdx.x * 256 + threadIdx.x;
    int d  = idx & (D_INNER - 1);
    int bl = idx >> 11;
    int l  = bl & (SEQLEN - 1);
    const float* base = xz + (size_t)bl * 4096 + d;
    float4 w = *(const float4*)(cw + d * 4);
    float s = cb[d];
    if (l >= 3) s = fmaf(base[-3 * 4096], w.x, s);
    if (l >= 2) s = fmaf(base[-2 * 4096], w.y, s);
    if (l >= 1) s = fmaf(base[-1 * 4096], w.z, s);
    s = fmaf(base[0], w.w, s);
    u[idx] = s * __builtin_amdgcn_rcpf(1.f + __expf(-s));
}

// ================= chunk-parallel selective scan (per-thread h[16]) ========
__global__ __launch_bounds__(256) void scan_partA(
        const float* __restrict__ delta, const float* __restrict__ u,
        const float* __restrict__ xdbl, const float* __restrict__ A_log,
        float* __restrict__ hF, float* __restrict__ sumd) {
    const int tid = threadIdx.x;
    const int bx  = blockIdx.x;
    const int seg = bx >> 4;
    const int b   = (bx >> 3) & 1;
    const int d   = (bx & 7) * 256 + tid;
    const int t0  = seg * TSEG;
    float An2[16];
    #pragma unroll
    for (int q = 0; q < 4; ++q) {
        float4 a = *(const float4*)(A_log + d * 16 + q * 4);
        An2[q*4+0] = -__expf(a.x) * LOG2E;
        An2[q*4+1] = -__expf(a.y) * LOG2E;
        An2[q*4+2] = -__expf(a.z) * LOG2E;
        An2[q*4+3] = -__expf(a.w) * LOG2E;
    }
    const float* dl = delta + ((size_t)b * SEQLEN + t0) * D_INNER + d;
    const float* uu = u     + ((size_t)b * SEQLEN + t0) * D_INNER + d;
    const float* bc = xdbl  + ((size_t)b * SEQLEN + t0) * 96 + 64;
    float h[16];
    #pragma unroll
    for (int n = 0; n < 16; ++n) h[n] = 0.f;
    float sd = 0.f;
    float pdv[4], puv[4];
    #pragma unroll
    for (int j = 0; j < 4; ++j) {
        pdv[j] = dl[(size_t)j * D_INNER];
        puv[j] = uu[(size_t)j * D_INNER];
    }
    for (int t4 = 0; t4 < TSEG; t4 += 4) {
        #pragma unroll
        for (int j = 0; j < 4; ++j) {
            const float dv = pdv[j], uv = puv[j];
            if (t4 + 4 < TSEG) {
                pdv[j] = dl[(size_t)(t4 + 4 + j) * D_INNER];
                puv[j] = uu[(size_t)(t4 + 4 + j) * D_INNER];
            }
            const float* bct = bc + (size_t)(t4 + j) * 96;
            float4 B0 = *(const float4*)(bct);
            float4 B1 = *(const float4*)(bct + 4);
            float4 B2 = *(const float4*)(bct + 8);
            float4 B3 = *(const float4*)(bct + 12);
            float Bv[16] = {B0.x,B0.y,B0.z,B0.w, B1.x,B1.y,B1.z,B1.w,
                            B2.x,B2.y,B2.z,B2.w, B3.x,B3.y,B3.z,B3.w};
            const float dvuv = dv * uv;
            sd += dv;
            #pragma unroll
            for (int n = 0; n < 16; ++n)
                h[n] = fmaf(exp2f(dv * An2[n]), h[n], dvuv * Bv[n]);
        }
    }
    const size_t o = (size_t)seg * (BATCH * D_INNER) + (size_t)b * D_INNER + d;
    #pragma unroll
    for (int q = 0; q < 4; ++q)
        *(float4*)(hF + o * 16 + q * 4) =
            make_float4(h[q*4], h[q*4+1], h[q*4+2], h[q*4+3]);
    sumd[o] = sd;
}

__global__ __launch_bounds__(256) void scan_combine(
        const float* __restrict__ A_log, float* __restrict__ hFin,
        const float* __restrict__ sumd) {
    int idx = blockIdx.x * 256 + threadIdx.x;
    int n = idx & 15, row = idx >> 4;
    int d = row & (D_INNER - 1);
    float An = -__expf(A_log[d * 16 + n]);
    float f[NSEG], p[NSEG];
    #pragma unroll
    for (int s = 0; s < NSEG; ++s) {
        size_t o = (size_t)s * (BATCH * D_INNER) + row;
        f[s] = hFin[o * 16 + n];
        p[s] = __expf(An * sumd[o]);
    }
    float h = 0.f;
    #pragma unroll
    for (int s = 0; s < NSEG; ++s) {
        size_t o = (size_t)s * (BATCH * D_INNER) + row;
        hFin[o * 16 + n] = h;
        h = fmaf(p[s], h, f[s]);
    }
}

__global__ __launch_bounds__(256) void scan_partB(
        const float* delta, const float* __restrict__ u,
        const float* __restrict__ xdbl, const float* __restrict__ xz,
        const float* __restrict__ A_log, const float* __restrict__ Dp,
        const float* __restrict__ hin, float* yg) {
    const int tid = threadIdx.x;
    const int bx  = blockIdx.x;
    const int seg = bx >> 4;
    const int b   = (bx >> 3) & 1;
    const int d   = (bx & 7) * 256 + tid;
    const int t0  = seg * TSEG;
    float An2[16];
    #pragma unroll
    for (int q = 0; q < 4; ++q) {
        float4 a = *(const float4*)(A_log + d * 16 + q * 4);
        An2[q*4+0] = -__expf(a.x) * LOG2E;
        An2[q*4+1] = -__expf(a.y) * LOG2E;
        An2[q*4+2] = -__expf(a.z) * LOG2E;
        An2[q*4+3] = -__expf(a.w) * LOG2E;
    }
    const float Dd = Dp[d];
    const float* dl = delta + ((size_t)b * SEQLEN + t0) * D_INNER + d;
    const float* uu = u     + ((size_t)b * SEQLEN + t0) * D_INNER + d;
    const float* bc = xdbl  + ((size_t)b * SEQLEN + t0) * 96 + 64;
    const float* zz = xz    + ((size_t)b * SEQLEN + t0) * 4096 + D_INNER + d;
    float* yo = yg + ((size_t)b * SEQLEN + t0) * D_INNER + d;
    const size_t o = (size_t)seg * (BATCH * D_INNER) + (size_t)b * D_INNER + d;
    float h[16];
    #pragma unroll
    for (int q = 0; q < 4; ++q) {
        float4 hv = *(const float4*)(hin + o * 16 + q * 4);
        h[q*4] = hv.x; h[q*4+1] = hv.y; h[q*4+2] = hv.z; h[q*4+3] = hv.w;
    }
    float pdv[4], puv[4], pzv[4];
    #pragma unroll
    for (int j = 0; j < 4; ++j) {
        pdv[j] = dl[(size_t)j * D_INNER];
        puv[j] = uu[(size_t)j * D_INNER];
        pzv[j] = zz[(size_t)j * 4096];
    }
    for (int t4 = 0; t4 < TSEG; t4 += 4) {
        #pragma unroll
        for (int j = 0; j < 4; ++j) {
            const float dv = pdv[j], uv = puv[j], zv = pzv[j];
            if (t4 + 4 < TSEG) {
                pdv[j] = dl[(size_t)(t4 + 4 + j) * D_INNER];
                puv[j] = uu[(size_t)(t4 + 4 + j) * D_INNER];
                pzv[j] = zz[(size_t)(t4 + 4 + j) * 4096];
            }
            const float* bct = bc + (size_t)(t4 + j) * 96;
            float4 B0 = *(const float4*)(bct);
            float4 B1 = *(const float4*)(bct + 4);
            float4 B2 = *(const float4*)(bct + 8);
            float4 B3 = *(const float4*)(bct + 12);
            float4 C0 = *(const float4*)(bct + 16);
            float4 C1 = *(const float4*)(bct + 20);
            float4 C2 = *(const float4*)(bct + 24);
            float4 C3 = *(const float4*)(bct + 28);
            float Bv[16] = {B0.x,B0.y,B0.z,B0.w, B1.x,B1.y,B1.z,B1.w,
                            B2.x,B2.y,B2.z,B2.w, B3.x,B3.y,B3.z,B3.w};
            float Cv[16] = {C0.x,C0.y,C0.z,C0.w, C1.x,C1.y,C1.z,C1.w,
                            C2.x,C2.y,C2.z,C2.w, C3.x,C3.y,C3.z,C3.w};
            const float dvuv = dv * uv;
            #pragma unroll
            for (int n = 0; n < 16; ++n)
                h[n] = fmaf(exp2f(dv * An2[n]), h[n], dvuv * Bv[n]);
            float acc[4] = {0.f, 0.f, 0.f, 0.f};
            #pragma unroll
            for (int n = 0; n < 16; ++n)
                acc[n & 3] = fmaf(h[n], Cv[n], acc[n & 3]);
            float yv = fmaf(uv, Dd, (acc[0] + acc[1]) + (acc[2] + acc[3]));
            float sig = zv * __builtin_amdgcn_rcpf(1.f + __expf(-zv));
            yo[(size_t)(t4 + j) * D_INNER] = yv * sig;
        }
    }
}

extern "C" void kernel_launch(void* const* d_in, const int* in_sizes, int n_in,
                              void* d_out, int out_size, void* d_ws, size_t ws_size,
                              hipStream_t stream) {
    const float* x        = (const float*)d_in[0];
    const float* w_in     = (const float*)d_in[1];
    const float* lA_in    = (const float*)d_in[2];
    const float* lB_in    = (const float*)d_in[3];
    const float* mask_in  = (const float*)d_in[4];
    const float* conv_w   = (const float*)d_in[5];
    const float* conv_b   = (const float*)d_in[6];
    const float* w_xp     = (const float*)d_in[7];
    const float* w_dt     = (const float*)d_in[8];
    const float* b_dt     = (const float*)d_in[9];
    const float* A_log    = (const float*)d_in[10];
    const float* Dp       = (const float*)d_in[11];
    const float* w_out    = (const float*)d_in[12];
    const float* lA_out   = (const float*)d_in[13];
    const float* lB_out   = (const float*)d_in[14];
    const float* mask_out = (const float*)d_in[15];

    // f32 workspace layout
    float* ws    = (float*)d_ws;
    float* xz    = ws;                              // [BL,4096]
    float* u     = xz    + (size_t)BL * 4096;       // [BL,2048]
    float* delta = u     + (size_t)BL * D_INNER;    // [BL,2048] (also yg)
    float* xdbl  = delta + (size_t)BL * D_INNER;    // [BL,96]
    float* t16   = xdbl  + (size_t)BL * 96;         // [BL,16]
    float* lbin  = t16   + (size_t)BL * 16;         // [4096,16]
    float* lbout = lbin  + (size_t)4096 * 16;       // [1024,16]

    // bf16 arenas in dead f32 regions
    const size_t AS_IN = (size_t)4096 * 1056, WS_IN = (size_t)4096 * 1056;
    unsigned short* Ahi_in = (unsigned short*)u;
    unsigned short* Alo_in = Ahi_in + AS_IN;
    unsigned short* Whi_in = Alo_in + AS_IN;
    unsigned short* Wlo_in = Whi_in + WS_IN;

    unsigned short* dtb = (unsigned short*)d_out;
    unsigned short* Ahi_dt = dtb;
    unsigned short* Alo_dt = Ahi_dt + (size_t)4096 * 64;
    unsigned short* Whi_dt = Alo_dt + (size_t)4096 * 64;
    unsigned short* Wlo_dt = Whi_dt + (size_t)2048 * 64;

    const size_t AS_OUT = (size_t)4096 * 2080, WS_OUT = (size_t)1024 * 2080;
    unsigned short* Ahi_out = (unsigned short*)xz;
    unsigned short* Alo_out = Ahi_out + AS_OUT;
    unsigned short* Whi_out = Alo_out + AS_OUT;
    unsigned short* Wlo_out = Whi_out + WS_OUT;

    // d_out f32 scratch (pre-final uses)
    float* outf    = (float*)d_out;
    float* xp_part = outf;                                  // [SKX][BL*96]
    float* hFin    = outf;                                  // [NSEG][4096][16]
    float* sumd    = hFin + (size_t)NSEG * BATCH * D_INNER * 16;

    // 1) LoRA premultiply + t16_in
    premul_kernel<<<(4096 * 16 + 255) / 256, 256, 0, stream>>>(lB_in, mask_in, lbin, 4096 * 16);
    premul_kernel<<<(1024 * 16 + 255) / 256, 256, 0, stream>>>(lB_out, mask_out, lbout, 1024 * 16);
    lora_t_kernel<<<BL, 256, 0, stream>>>(x, D_MODEL, lA_in, D_MODEL, t16);
    // 2) hi/lo conversions for in_proj (K=1024, KP=1056)
    hilo_kernel<<<4096, 256, 0, stream>>>(x,    1024, 256, 1056, Ahi_in, Alo_in, 4096 * 256);
    hilo_kernel<<<4096, 256, 0, stream>>>(w_in, 1024, 256, 1056, Whi_in, Wlo_in, 4096 * 256);
    ext_kernel<<<512, 256, 0, stream>>>(t16,  1024, 1056, Ahi_in, Alo_in, 4096);
    ext_kernel<<<512, 256, 0, stream>>>(lbin, 1024, 1056, Whi_in, Wlo_in, 4096);
    // 3) in_proj MFMA GEMM -> xz
    mfma_gemm<0><<<dim3(32, 32), 256, 0, stream>>>(
        Ahi_in, Alo_in, Whi_in, Wlo_in, 1056, xz, 4096, nullptr);
    // 4) u = silu(conv(xs) + b)
    conv_silu_kernel<<<(BL * D_INNER) / 256, 256, 0, stream>>>(xz, conv_w, conv_b, u);
    // 5) x_proj split-K fp32 -> xdbl
    gemm_f32_kernel<<<dim3(1, BL / 128, SKX), 256, 0, stream>>>(
        u, D_INNER, w_xp, D_INNER, xp_part, 96, BL, 96, KCH, KCH);
    sk_reduce_kernel<<<(BL * 96 + 255) / 256, 256, 0, stream>>>(xp_part, xdbl, BL * 96);
    // 6) dt_proj MFMA (K=64) -> delta = softplus(. + b_dt)
    hilo_kernel<<<(4096 * 16 + 255) / 256, 256, 0, stream>>>(xdbl, 96, 16, 64, Ahi_dt, Alo_dt, 4096 * 16);
    hilo_kernel<<<(2048 * 16 + 255) / 256, 256, 0, stream>>>(w_dt, 64, 16, 64, Whi_dt, Wlo_dt, 2048 * 16);
    mfma_gemm<2><<<dim3(16, 32), 256, 0, stream>>>(
        Ahi_dt, Alo_dt, Whi_dt, Wlo_dt, 64, delta, 2048, b_dt);
    // 7) chunk-parallel selective scan (+ gating); yg aliases delta
    scan_partA<<<NSEG * BATCH * 8, 256, 0, stream>>>(delta, u, xdbl, A_log, hFin, sumd);
    scan_combine<<<(BATCH * D_INNER * 16) / 256, 256, 0, stream>>>(A_log, hFin, sumd);
    scan_partB<<<NSEG * BATCH * 8, 256, 0, stream>>>(delta, u, xdbl, xz, A_log, Dp, hFin, delta);
    // 8) out_proj: t16_out, conversions (K=2048, KP=2080), MFMA -> d_out
    lora_t_kernel<<<BL, 256, 0, stream>>>(delta, D_INNER, lA_out, D_INNER, t16);
    hilo_kernel<<<8192, 256, 0, stream>>>(delta, 2048, 512, 2080, Ahi_out, Alo_out, 4096 * 512);
    hilo_kernel<<<2048, 256, 0, stream>>>(w_out, 2048, 512, 2080, Whi_out, Wlo_out, 1024 * 512);
    ext_kernel<<<512, 256, 0, stream>>>(t16,   2048, 2080, Ahi_out, Alo_out, 4096);
    ext_kernel<<<128, 256, 0, stream>>>(lbout, 2048, 2080, Whi_out, Wlo_out, 1024);
    mfma_gemm<0><<<dim3(8, 32), 256, 0, stream>>>(
        Ahi_out, Alo_out, Whi_out, Wlo_out, 2080, (float*)d_out, 1024, nullptr);
}